// Round 6
// baseline (4939.413 us; speedup 1.0000x reference)
//
#include <hip/hip_runtime.h>
#include <hip/hip_bf16.h>

typedef unsigned short u16;
using short8 = __attribute__((ext_vector_type(8))) short;
using f32x4  = __attribute__((ext_vector_type(4))) float;

#define DEVINL static __device__ __forceinline__

DEVINL float bf2f(u16 u){
  union { unsigned int i; float f; } x; x.i = ((unsigned int)u) << 16; return x.f;
}
DEVINL u16 f2bf(float f){
  union { float f; unsigned int i; } x; x.f = f;
  unsigned int i = x.i;
  return (u16)((i + 0x7FFFu + ((i >> 16) & 1u)) >> 16);
}
// 1-instruction bf16 convert (v_cvt_pk_bf16_f32 path via HIP intrinsic)
DEVINL u16 f2bf1(float f){
  __hip_bfloat16 b = __float2bfloat16(f);
  u16 u; __builtin_memcpy(&u, &b, 2); return u;
}
// fast gates: v_exp_f32 (2^x) + v_rcp_f32, no IEEE-div sequences
DEVINL float fast_sigm(float x){
  float e = __builtin_amdgcn_exp2f(x * -1.442695041f);
  return __builtin_amdgcn_rcpf(1.f + e);
}
DEVINL float fast_tanh(float x){
  x = fminf(fmaxf(x, -10.f), 10.f);
  float e = __builtin_amdgcn_exp2f(x * -2.885390082f);
  return (1.f - e) * __builtin_amdgcn_rcpf(1.f + e);
}
DEVINL f32x4 zero4(){ f32x4 z = {0.f, 0.f, 0.f, 0.f}; return z; }

DEVINL f32x4 mfma16(short8 a, short8 b, f32x4 c){
  return __builtin_amdgcn_mfma_f32_16x16x32_bf16(a, b, c, 0, 0, 0);
}

// lane l: row = l&15, k0 = (l>>4)*8 ; 16B vector read. stride in u16 elements (rows 16B-aligned)
DEVINL short8 frag_ld(const u16* base, int stride){
  int l = threadIdx.x & 63;
  return *(const short8*)(base + (l & 15) * stride + ((l >> 4) << 3));
}
// fragment load directly from global, row stride in u16, ks selects 32-col K slice
DEVINL short8 gfrag(const u16* rowbase, int stride, int ks){
  int l = threadIdx.x & 63;
  return *(const short8*)(rowbase + (size_t)(l & 15) * stride + ks * 32 + ((l >> 4) << 3));
}

// acc layout: col = lane&15 (+col_base), rows = (lane>>4)*4 + r
DEVINL void acc_store_lds(u16* dst, int stride, int col_base, f32x4 acc, float bias, bool relu){
  int l = threadIdx.x & 63;
  int col = col_base + (l & 15);
  int row0 = (l >> 4) * 4;
  #pragma unroll
  for (int r = 0; r < 4; r++){
    float v = acc[r] + bias;
    if (relu) v = fmaxf(v, 0.f);
    dst[(row0 + r) * stride + col] = f2bf(v);
  }
}

// stage fp32 (N,K) row-major weights -> bf16 LDS [N][Kp+8]; zero cols K..Kp
DEVINL void stage_weights(u16* dst, const float* src, int N, int K, int Kp){
  int stride = Kp + 8;
  if (Kp > K){
    int padw = Kp - K;
    for (int i = threadIdx.x; i < N * padw; i += blockDim.x){
      int n = i / padw, k = K + (i - (i / padw) * padw);
      dst[n * stride + k] = 0;
    }
  }
  for (int i = threadIdx.x * 4; i < N * K; i += blockDim.x * 4){
    float4 v = *(const float4*)(src + i);
    int n = i / K, k = i - n * K;
    u16* d = dst + n * stride + k;
    d[0] = f2bf(v.x); d[1] = f2bf(v.y); d[2] = f2bf(v.z); d[3] = f2bf(v.w);
  }
}

__global__ __launch_bounds__(256) void k_inith(const float* __restrict__ h0, u16* __restrict__ hst){
  int i = blockIdx.x * 256 + threadIdx.x;
  if (i < 2 * 1024 * 128) hst[i] = f2bf(h0[i]);
}

// ---------------- phase A: phi_u, per-wave independent tiles, no inner barriers ----------------
__global__ __launch_bounds__(512, 4) void k_phiu(const float* __restrict__ u,
    const float* __restrict__ w0, const float* __restrict__ b0,
    const float* __restrict__ w1, const float* __restrict__ b1,
    u16* __restrict__ phi, int t0, int Tc){
  __shared__ __align__(16) u16 w0s[128 * 40];
  __shared__ __align__(16) u16 w1s[128 * 136];
  __shared__ __align__(16) u16 buf[8][16 * 136];
  stage_weights(w0s, w0, 128, 16, 32);
  stage_weights(w1s, w1, 128, 128, 128);
  int wv = threadIdx.x >> 6, l = threadIdx.x & 63;
  u16* mybuf = buf[wv];
  float b0v[8], b1v[8];
  #pragma unroll
  for (int nt = 0; nt < 8; nt++){
    b0v[nt] = b0[nt * 16 + (l & 15)];
    b1v[nt] = b1[nt * 16 + (l & 15)];
  }
  __syncthreads();
  int tpb = Tc >> 4;
  int ntile = 1024 * tpb;
  int stride = gridDim.x * 8;
  for (int tile = blockIdx.x * 8 + wv; tile < ntile; tile += stride){
    int b = tile / tpb;
    int tt = (tile - b * tpb) << 4;
    int t = l & 15, kb = l >> 4;
    #pragma unroll
    for (int j = 0; j < 4; j++){
      int k = kb + j * 4;
      mybuf[t * 136 + k] = f2bf(u[(size_t)(b * 16 + k) * 1024 + t0 + tt + t]);
      mybuf[t * 136 + 16 + k] = 0;
    }
    short8 a0 = frag_ld(mybuf, 136);
    f32x4 acc[8];
    #pragma unroll
    for (int nt = 0; nt < 8; nt++)
      acc[nt] = mfma16(a0, frag_ld(w0s + nt * 16 * 40, 40), zero4());
    #pragma unroll
    for (int nt = 0; nt < 8; nt++)
      acc_store_lds(mybuf, 136, nt * 16, acc[nt], b0v[nt], true);
    f32x4 a2[8];
    #pragma unroll
    for (int nt = 0; nt < 8; nt++) a2[nt] = zero4();
    #pragma unroll
    for (int ks = 0; ks < 4; ks++){
      short8 a = frag_ld(mybuf + ks * 32, 136);
      #pragma unroll
      for (int nt = 0; nt < 8; nt++)
        a2[nt] = mfma16(a, frag_ld(w1s + nt * 16 * 136 + ks * 32, 136), a2[nt]);
    }
    #pragma unroll
    for (int nt = 0; nt < 8; nt++)
      acc_store_lds(mybuf, 136, nt * 16, a2[nt], b1v[nt], false);
    u16* dst = phi + (size_t)(b * Tc + tt) * 128;
    #pragma unroll
    for (int j = 0; j < 4; j++){
      int c = j * 64 + l;
      int row = c >> 4, k = (c & 15) * 8;
      *(short8*)(dst + row * 128 + k) = *(const short8*)(mybuf + row * 136 + k);
    }
  }
}

// ---------------- phase B: 2-layer GRU, 16 rows/block x 64 blocks ----------------
// Layer-pipelined, 1 barrier/iter. All 4 weight matrices register(AGPR)-resident.
// h tiles in row-major padded LDS [16][136] (b128 frag reads hit the 8cy BW floor).
// phi A-fragments read directly from global (L2), 2-iteration register prefetch.
__global__ __launch_bounds__(512, 1) void k_gru(const u16* __restrict__ phi,
    const float* __restrict__ gwih, const float* __restrict__ gwhh,
    u16* __restrict__ hst, u16* __restrict__ Hs, int Tc){
  __shared__ __align__(16) u16 h0s[2][16 * 136];
  __shared__ __align__(16) u16 h1s[2][16 * 136];
  const int wv = threadIdx.x >> 6, l = threadIdx.x & 63;
  const int b0 = blockIdx.x * 16;
  const int m0 = (l >> 4) * 4;
  const int colw = wv * 16 + (l & 15);

  // stationary register weights: W[0]=wih0, W[1]=whh0, W[2]=wih1, W[3]=whh1
  const float* srcs[4] = { gwih, gwhh, gwih + 49152, gwhh + 49152 };
  short8 W[4][3][4];
  #pragma unroll
  for (int mm = 0; mm < 4; mm++){
    #pragma unroll
    for (int g = 0; g < 3; g++){
      int n = g * 128 + colw;
      #pragma unroll
      for (int ks = 0; ks < 4; ks++){
        const float* p = srcs[mm] + (size_t)n * 128 + ks * 32 + ((l >> 4) << 3);
        float4 va = *(const float4*)p;
        float4 vb = *(const float4*)(p + 4);
        short8 f;
        f[0] = (short)f2bf(va.x); f[1] = (short)f2bf(va.y);
        f[2] = (short)f2bf(va.z); f[3] = (short)f2bf(va.w);
        f[4] = (short)f2bf(vb.x); f[5] = (short)f2bf(vb.y);
        f[6] = (short)f2bf(vb.z); f[7] = (short)f2bf(vb.w);
        W[mm][g][ks] = f;
      }
    }
  }
  // restore state into row-major padded LDS
  {
    int row = threadIdx.x >> 5, k0 = (threadIdx.x & 31) * 4;
    *(uint2*)(&h0s[0][row * 136 + k0]) =
        *(const uint2*)(hst + (size_t)(b0 + row) * 128 + k0);
    *(uint2*)(&h1s[0][row * 136 + k0]) =
        *(const uint2*)(hst + 131072 + (size_t)(b0 + row) * 128 + k0);
  }
  float hp0[4], hp1[4];
  #pragma unroll
  for (int r = 0; r < 4; r++){
    hp0[r] = bf2f(hst[(size_t)(b0 + m0 + r) * 128 + colw]);
    hp1[r] = bf2f(hst[131072 + (size_t)(b0 + m0 + r) * 128 + colw]);
  }
  // phi fragment pointer for this lane; prefetch t=0 (pfA) and t=1 (pfB)
  const u16* pbase = phi + (size_t)(b0 + (l & 15)) * Tc * 128 + ((l >> 4) << 3);
  short8 pfA[4], pfB[4];
  #pragma unroll
  for (int ks = 0; ks < 4; ks++){
    pfA[ks] = *(const short8*)(pbase + ks * 32);
    pfB[ks] = *(const short8*)(pbase + 128 + ks * 32);
  }
  __syncthreads();

  // iteration i (parity P=i&1, compile-time via 2-unroll):
  //   layer1: H1[i] = f(H1[i-1](h1s[P^1]), H0[i](h0s[P]))  [i>0] -> h1s[P]
  //   layer0: H0[i+1] = f(H0[i](h0s[P]), phi(i)(pfU))       [i<Tc] -> h0s[P^1]
  //   Hs(i-1) <- h1s[P^1]; pfU reloaded with phi(i+2).
  auto ITER = [&](int i, int P, short8 (&pfU)[4]){
    short8 a0[4];
    #pragma unroll
    for (int ks = 0; ks < 4; ks++) a0[ks] = frag_ld(h0s[P] + ks * 32, 136);
    if (i > 0){
      short8 a1[4];
      #pragma unroll
      for (int ks = 0; ks < 4; ks++) a1[ks] = frag_ld(h1s[P ^ 1] + ks * 32, 136);
      {
        int row = threadIdx.x >> 5, k0 = (threadIdx.x & 31) * 4;
        *(uint2*)(Hs + ((size_t)(b0 + row) * Tc + (i - 1)) * 128 + k0) =
            *(const uint2*)(&h1s[P ^ 1][row * 136 + k0]);
      }
      f32x4 xr = zero4(), xz = zero4(), xn = zero4();
      f32x4 hr = zero4(), hz = zero4(), hh = zero4();
      #pragma unroll
      for (int ks = 0; ks < 4; ks++){
        xr = mfma16(a0[ks], W[2][0][ks], xr);
        xz = mfma16(a0[ks], W[2][1][ks], xz);
        xn = mfma16(a0[ks], W[2][2][ks], xn);
        hr = mfma16(a1[ks], W[3][0][ks], hr);
        hz = mfma16(a1[ks], W[3][1][ks], hz);
        hh = mfma16(a1[ks], W[3][2][ks], hh);
      }
      #pragma unroll
      for (int r = 0; r < 4; r++){
        float rg = fast_sigm(xr[r] + hr[r]);
        float zg = fast_sigm(xz[r] + hz[r]);
        float ng = fast_tanh(xn[r] + rg * hh[r]);
        float hv = zg * (hp1[r] - ng) + ng;
        hp1[r] = hv;
        h1s[P][(m0 + r) * 136 + colw] = f2bf1(hv);
      }
    }
    if (i < Tc){
      f32x4 xr = zero4(), xz = zero4(), xn = zero4();
      f32x4 hr = zero4(), hz = zero4(), hh = zero4();
      #pragma unroll
      for (int ks = 0; ks < 4; ks++){
        xr = mfma16(pfU[ks], W[0][0][ks], xr);
        xz = mfma16(pfU[ks], W[0][1][ks], xz);
        xn = mfma16(pfU[ks], W[0][2][ks], xn);
        hr = mfma16(a0[ks], W[1][0][ks], hr);
        hz = mfma16(a0[ks], W[1][1][ks], hz);
        hh = mfma16(a0[ks], W[1][2][ks], hh);
      }
      // reload pfU with phi(i+2) (used 2 iterations later; vmcnt waited at use)
      if (i + 2 < Tc){
        const u16* p2 = pbase + (size_t)(i + 2) * 128;
        #pragma unroll
        for (int ks = 0; ks < 4; ks++)
          pfU[ks] = *(const short8*)(p2 + ks * 32);
      }
      #pragma unroll
      for (int r = 0; r < 4; r++){
        float rg = fast_sigm(xr[r] + hr[r]);
        float zg = fast_sigm(xz[r] + hz[r]);
        float ng = fast_tanh(xn[r] + rg * hh[r]);
        float hv = zg * (hp0[r] - ng) + ng;
        hp0[r] = hv;
        h0s[P ^ 1][(m0 + r) * 136 + colw] = f2bf1(hv);
      }
    }
    asm volatile("s_waitcnt lgkmcnt(0)" ::: "memory");
    __builtin_amdgcn_s_barrier();
    asm volatile("" ::: "memory");
  };

  ITER(0, 0, pfA);
  for (int i = 1; i < Tc; i += 2){
    ITER(i, 1, pfB);
    ITER(i + 1, 0, pfA);
  }
  // save state (Tc even: H0[Tc] in h0s[0], H1[Tc] in h1s[0])
  {
    int row = threadIdx.x >> 5, k0 = (threadIdx.x & 31) * 4;
    *(uint2*)(hst + (size_t)(b0 + row) * 128 + k0) =
        *(const uint2*)(&h0s[0][row * 136 + k0]);
    *(uint2*)(hst + 131072 + (size_t)(b0 + row) * 128 + k0) =
        *(const uint2*)(&h1s[0][row * 136 + k0]);
  }
}

// ---------------- phase C1: dynn + x_mean/x_logvar, per-wave tiles ----------------
__global__ __launch_bounds__(512, 2) void k_c1(const u16* __restrict__ phi, const u16* __restrict__ Hs,
    const float* __restrict__ dw0, const float* __restrict__ db0,
    const float* __restrict__ dw1, const float* __restrict__ db1,
    const float* __restrict__ xmw, const float* __restrict__ xmb,
    const float* __restrict__ xlw, const float* __restrict__ xlb,
    u16* __restrict__ xmlv, int Tc){
  __shared__ __align__(16) u16 w0s[128 * 264];
  __shared__ __align__(16) u16 w1s[128 * 136];
  __shared__ __align__(16) u16 xws[32 * 136];
  __shared__ __align__(16) u16 buf[8][16 * 136];
  stage_weights(w0s, dw0, 128, 256, 256);
  stage_weights(w1s, dw1, 128, 128, 128);
  stage_weights(xws, xmw, 16, 128, 128);
  stage_weights(xws + 16 * 136, xlw, 16, 128, 128);
  int wv = threadIdx.x >> 6, l = threadIdx.x & 63;
  u16* mybuf = buf[wv];
  float b0v[8], b1v[8];
  #pragma unroll
  for (int nt = 0; nt < 8; nt++){
    b0v[nt] = db0[nt * 16 + (l & 15)];
    b1v[nt] = db1[nt * 16 + (l & 15)];
  }
  float bxm = xmb[l & 15], bxl = xlb[l & 15];
  __syncthreads();
  int tpb = Tc >> 4;
  int ntile = 1024 * tpb;
  int stride = gridDim.x * 8;
  for (int tile = blockIdx.x * 8 + wv; tile < ntile; tile += stride){
    int b = tile / tpb;
    int tt = (tile - b * tpb) << 4;
    size_t rbase = (size_t)(b * Tc + tt);
    const u16* ap = phi + rbase * 128;
    const u16* hp = Hs + rbase * 128;
    f32x4 acc[8];
    #pragma unroll
    for (int nt = 0; nt < 8; nt++) acc[nt] = zero4();
    #pragma unroll
    for (int ks = 0; ks < 8; ks++){
      short8 a = (ks < 4) ? gfrag(ap, 128, ks) : gfrag(hp, 128, ks - 4);
      #pragma unroll
      for (int nt = 0; nt < 8; nt++)
        acc[nt] = mfma16(a, frag_ld(w0s + nt * 16 * 264 + ks * 32, 264), acc[nt]);
    }
    #pragma unroll
    for (int nt = 0; nt < 8; nt++)
      acc_store_lds(mybuf, 136, nt * 16, acc[nt], b0v[nt], true);
    f32x4 a2[8];
    #pragma unroll
    for (int nt = 0; nt < 8; nt++) a2[nt] = zero4();
    #pragma unroll
    for (int ks = 0; ks < 4; ks++){
      short8 a = frag_ld(mybuf + ks * 32, 136);
      #pragma unroll
      for (int nt = 0; nt < 8; nt++)
        a2[nt] = mfma16(a, frag_ld(w1s + nt * 16 * 136 + ks * 32, 136), a2[nt]);
    }
    #pragma unroll
    for (int nt = 0; nt < 8; nt++)
      acc_store_lds(mybuf, 136, nt * 16, a2[nt], b1v[nt], false);
    f32x4 am = zero4(), al = zero4();
    #pragma unroll
    for (int ks = 0; ks < 4; ks++){
      short8 a = frag_ld(mybuf + ks * 32, 136);
      am = mfma16(a, frag_ld(xws + ks * 32, 136), am);
      al = mfma16(a, frag_ld(xws + 16 * 136 + ks * 32, 136), al);
    }
    acc_store_lds(mybuf, 136, 0, am, bxm, false);
    acc_store_lds(mybuf, 136, 16, al, bxl, false);
    u16* dst = xmlv + rbase * 32;
    int c = l;
    int row = c >> 2, k = (c & 3) * 8;
    *(short8*)(dst + row * 32 + k) = *(const short8*)(mybuf + row * 136 + k);
  }
}

// ---------------- phase C2: phi_x + menn + C@x_mean + loss, per-wave tiles ----------------
__global__ __launch_bounds__(512, 2) void k_c2(const u16* __restrict__ xmlv, const float* __restrict__ y,
    const float* __restrict__ pw0, const float* __restrict__ pb0,
    const float* __restrict__ pw1, const float* __restrict__ pb1,
    const float* __restrict__ mw0, const float* __restrict__ mb0,
    const float* __restrict__ mw1, const float* __restrict__ mb1,
    const float* __restrict__ Cw, float* __restrict__ out, int t0, int Tc){
  __shared__ __align__(16) u16 pw0s[128 * 40];
  __shared__ __align__(16) u16 pw1s[128 * 136];
  __shared__ __align__(16) u16 mw0s[128 * 136];
  __shared__ __align__(16) u16 mw1s[16 * 136];
  __shared__ __align__(16) u16 Cs[16 * 40];
  __shared__ __align__(16) u16 buf[8][16 * 136];
  stage_weights(pw0s, pw0, 128, 32, 32);
  stage_weights(pw1s, pw1, 128, 128, 128);
  stage_weights(mw0s, mw0, 128, 128, 128);
  stage_weights(mw1s, mw1, 16, 128, 128);
  stage_weights(Cs, Cw, 16, 16, 32);
  int wv = threadIdx.x >> 6, l = threadIdx.x & 63;
  u16* mybuf = buf[wv];
  float bp0v[8], bp1v[8], bm0v[8];
  #pragma unroll
  for (int nt = 0; nt < 8; nt++){
    bp0v[nt] = pb0[nt * 16 + (l & 15)];
    bp1v[nt] = pb1[nt * 16 + (l & 15)];
    bm0v[nt] = mb0[nt * 16 + (l & 15)];
  }
  float bm1 = mb1[l & 15];
  __syncthreads();
  float lacc = 0.f;
  int tpb = Tc >> 4;
  int ntile = 1024 * tpb;
  int stride = gridDim.x * 8;
  for (int tile = blockIdx.x * 8 + wv; tile < ntile; tile += stride){
    int b = tile / tpb;
    int tt = (tile - b * tpb) << 4;
    size_t rbase = (size_t)(b * Tc + tt);
    const u16* xp = xmlv + rbase * 32;
    short8 a0 = gfrag(xp, 32, 0);
    f32x4 acc[8];
    #pragma unroll
    for (int nt = 0; nt < 8; nt++)
      acc[nt] = mfma16(a0, frag_ld(pw0s + nt * 16 * 40, 40), zero4());
    #pragma unroll
    for (int nt = 0; nt < 8; nt++)
      acc_store_lds(mybuf, 136, nt * 16, acc[nt], bp0v[nt], true);
    f32x4 a2[8];
    #pragma unroll
    for (int nt = 0; nt < 8; nt++) a2[nt] = zero4();
    #pragma unroll
    for (int ks = 0; ks < 4; ks++){
      short8 a = frag_ld(mybuf + ks * 32, 136);
      #pragma unroll
      for (int nt = 0; nt < 8; nt++)
        a2[nt] = mfma16(a, frag_ld(pw1s + nt * 16 * 136 + ks * 32, 136), a2[nt]);
    }
    #pragma unroll
    for (int nt = 0; nt < 8; nt++)
      acc_store_lds(mybuf, 136, nt * 16, a2[nt], bp1v[nt], false);
    f32x4 a3[8];
    #pragma unroll
    for (int nt = 0; nt < 8; nt++) a3[nt] = zero4();
    #pragma unroll
    for (int ks = 0; ks < 4; ks++){
      short8 a = frag_ld(mybuf + ks * 32, 136);
      #pragma unroll
      for (int nt = 0; nt < 8; nt++)
        a3[nt] = mfma16(a, frag_ld(mw0s + nt * 16 * 136 + ks * 32, 136), a3[nt]);
    }
    #pragma unroll
    for (int nt = 0; nt < 8; nt++)
      acc_store_lds(mybuf, 136, nt * 16, a3[nt], bm0v[nt], true);
    f32x4 ay = zero4();
    #pragma unroll
    for (int ks = 0; ks < 4; ks++){
      short8 a = frag_ld(mybuf + ks * 32, 136);
      ay = mfma16(a, frag_ld(mw1s + ks * 32, 136), ay);
    }
    f32x4 ac = mfma16(a0, frag_ld(Cs, 40), zero4());
    #pragma unroll
    for (int r = 0; r < 4; r++){
      float yh = ay[r] + bm1 + ac[r];
      int m = (l >> 4) * 4 + r, j = l & 15;
      float d = yh - y[(size_t)(b * 16 + j) * 1024 + t0 + tt + m];
      lacc += d * d;
    }
  }
  #pragma unroll
  for (int off = 32; off > 0; off >>= 1)
    lacc += __shfl_down(lacc, off);
  if (l == 0) atomicAdd(out, lacc);
}

extern "C" void kernel_launch(void* const* d_in, const int* in_sizes, int n_in,
                              void* d_out, int out_size, void* d_ws, size_t ws_size,
                              hipStream_t stream){
  const float* u    = (const float*)d_in[0];
  const float* y    = (const float*)d_in[1];
  const float* h0   = (const float*)d_in[2];
  const float* puw0 = (const float*)d_in[3];
  const float* pub0 = (const float*)d_in[4];
  const float* puw1 = (const float*)d_in[5];
  const float* pub1 = (const float*)d_in[6];
  const float* dw0  = (const float*)d_in[7];
  const float* db0  = (const float*)d_in[8];
  const float* dw1  = (const float*)d_in[9];
  const float* db1  = (const float*)d_in[10];
  const float* xmw  = (const float*)d_in[11];
  const float* xmb  = (const float*)d_in[12];
  const float* xlw  = (const float*)d_in[13];
  const float* xlb  = (const float*)d_in[14];
  const float* pxw0 = (const float*)d_in[15];
  const float* pxb0 = (const float*)d_in[16];
  const float* pxw1 = (const float*)d_in[17];
  const float* pxb1 = (const float*)d_in[18];
  const float* mw0  = (const float*)d_in[19];
  const float* mb0  = (const float*)d_in[20];
  const float* mw1  = (const float*)d_in[21];
  const float* mb1  = (const float*)d_in[22];
  const float* gwih = (const float*)d_in[23];
  const float* gwhh = (const float*)d_in[24];
  const float* Cw   = (const float*)d_in[25];

  char* w = (char*)d_ws;
  u16* hst = (u16*)w; w += (size_t)2 * 1024 * 128 * 2;
  size_t head = (size_t)2 * 1024 * 128 * 2 + 4096;
  size_t avail = (ws_size > head) ? (ws_size - head) : 0;
  int Tc = 1024;
  while (Tc > 64 && (size_t)1024 * (size_t)Tc * (128 + 128 + 32) * 2 > avail) Tc >>= 1;
  u16* phi  = (u16*)w; w += (size_t)1024 * Tc * 128 * 2;
  u16* Hs   = (u16*)w; w += (size_t)1024 * Tc * 128 * 2;
  u16* xmlv = (u16*)w; w += (size_t)1024 * Tc * 32 * 2;

  hipMemsetAsync(d_out, 0, sizeof(float), stream);
  k_inith<<<1024, 256, 0, stream>>>(h0, hst);
  for (int t0 = 0; t0 < 1024; t0 += Tc){
    k_phiu<<<512, 512, 0, stream>>>(u, puw0, pub0, puw1, pub1, phi, t0, Tc);
    k_gru<<<64, 512, 0, stream>>>(phi, gwih, gwhh, hst, Hs, Tc);
    k_c1<<<256, 512, 0, stream>>>(phi, Hs, dw0, db0, dw1, db1, xmw, xmb, xlw, xlb, xmlv, Tc);
    k_c2<<<256, 512, 0, stream>>>(xmlv, y, pxw0, pxb0, pxw1, pxb1, mw0, mb0, mw1, mb1, Cw,
                                  (float*)d_out, t0, Tc);
  }
}

// Round 7
// 3606.616 us; speedup vs baseline: 1.3695x; 1.3695x over previous
//
#include <hip/hip_runtime.h>
#include <hip/hip_bf16.h>

typedef unsigned short u16;
using short8 = __attribute__((ext_vector_type(8))) short;
using f32x4  = __attribute__((ext_vector_type(4))) float;

#define DEVINL static __device__ __forceinline__

DEVINL float bf2f(u16 u){
  union { unsigned int i; float f; } x; x.i = ((unsigned int)u) << 16; return x.f;
}
DEVINL u16 f2bf(float f){
  union { float f; unsigned int i; } x; x.f = f;
  unsigned int i = x.i;
  return (u16)((i + 0x7FFFu + ((i >> 16) & 1u)) >> 16);
}
// 1-instruction bf16 convert
DEVINL u16 f2bf1(float f){
  __hip_bfloat16 b = __float2bfloat16(f);
  u16 u; __builtin_memcpy(&u, &b, 2); return u;
}
// fast gates: v_exp_f32 (2^x) + v_rcp_f32, no IEEE-div sequences
DEVINL float fast_sigm(float x){
  float e = __builtin_amdgcn_exp2f(x * -1.442695041f);
  return __builtin_amdgcn_rcpf(1.f + e);
}
DEVINL float fast_tanh(float x){
  x = fminf(fmaxf(x, -10.f), 10.f);
  float e = __builtin_amdgcn_exp2f(x * -2.885390082f);
  return (1.f - e) * __builtin_amdgcn_rcpf(1.f + e);
}
DEVINL f32x4 zero4(){ f32x4 z = {0.f, 0.f, 0.f, 0.f}; return z; }

DEVINL f32x4 mfma16(short8 a, short8 b, f32x4 c){
  return __builtin_amdgcn_mfma_f32_16x16x32_bf16(a, b, c, 0, 0, 0);
}

// lane l: row = l&15, k0 = (l>>4)*8 ; 16B vector read. stride in u16 elements
DEVINL short8 frag_ld(const u16* base, int stride){
  int l = threadIdx.x & 63;
  return *(const short8*)(base + (l & 15) * stride + ((l >> 4) << 3));
}
DEVINL short8 gfrag(const u16* rowbase, int stride, int ks){
  int l = threadIdx.x & 63;
  return *(const short8*)(rowbase + (size_t)(l & 15) * stride + ks * 32 + ((l >> 4) << 3));
}

DEVINL void acc_store_lds(u16* dst, int stride, int col_base, f32x4 acc, float bias, bool relu){
  int l = threadIdx.x & 63;
  int col = col_base + (l & 15);
  int row0 = (l >> 4) * 4;
  #pragma unroll
  for (int r = 0; r < 4; r++){
    float v = acc[r] + bias;
    if (relu) v = fmaxf(v, 0.f);
    dst[(row0 + r) * stride + col] = f2bf(v);
  }
}

DEVINL void stage_weights(u16* dst, const float* src, int N, int K, int Kp){
  int stride = Kp + 8;
  if (Kp > K){
    int padw = Kp - K;
    for (int i = threadIdx.x; i < N * padw; i += blockDim.x){
      int n = i / padw, k = K + (i - (i / padw) * padw);
      dst[n * stride + k] = 0;
    }
  }
  for (int i = threadIdx.x * 4; i < N * K; i += blockDim.x * 4){
    float4 v = *(const float4*)(src + i);
    int n = i / K, k = i - n * K;
    u16* d = dst + n * stride + k;
    d[0] = f2bf(v.x); d[1] = f2bf(v.y); d[2] = f2bf(v.z); d[3] = f2bf(v.w);
  }
}

__global__ __launch_bounds__(256) void k_inith(const float* __restrict__ h0, u16* __restrict__ hst){
  int i = blockIdx.x * 256 + threadIdx.x;
  if (i < 2 * 1024 * 128) hst[i] = f2bf(h0[i]);
}

// ---------------- phase A: phi_u ----------------
__global__ __launch_bounds__(512, 4) void k_phiu(const float* __restrict__ u,
    const float* __restrict__ w0, const float* __restrict__ b0,
    const float* __restrict__ w1, const float* __restrict__ b1,
    u16* __restrict__ phi, int t0, int Tc){
  __shared__ __align__(16) u16 w0s[128 * 40];
  __shared__ __align__(16) u16 w1s[128 * 136];
  __shared__ __align__(16) u16 buf[8][16 * 136];
  stage_weights(w0s, w0, 128, 16, 32);
  stage_weights(w1s, w1, 128, 128, 128);
  int wv = threadIdx.x >> 6, l = threadIdx.x & 63;
  u16* mybuf = buf[wv];
  float b0v[8], b1v[8];
  #pragma unroll
  for (int nt = 0; nt < 8; nt++){
    b0v[nt] = b0[nt * 16 + (l & 15)];
    b1v[nt] = b1[nt * 16 + (l & 15)];
  }
  __syncthreads();
  int tpb = Tc >> 4;
  int ntile = 1024 * tpb;
  int stride = gridDim.x * 8;
  for (int tile = blockIdx.x * 8 + wv; tile < ntile; tile += stride){
    int b = tile / tpb;
    int tt = (tile - b * tpb) << 4;
    int t = l & 15, kb = l >> 4;
    #pragma unroll
    for (int j = 0; j < 4; j++){
      int k = kb + j * 4;
      mybuf[t * 136 + k] = f2bf(u[(size_t)(b * 16 + k) * 1024 + t0 + tt + t]);
      mybuf[t * 136 + 16 + k] = 0;
    }
    short8 a0 = frag_ld(mybuf, 136);
    f32x4 acc[8];
    #pragma unroll
    for (int nt = 0; nt < 8; nt++)
      acc[nt] = mfma16(a0, frag_ld(w0s + nt * 16 * 40, 40), zero4());
    #pragma unroll
    for (int nt = 0; nt < 8; nt++)
      acc_store_lds(mybuf, 136, nt * 16, acc[nt], b0v[nt], true);
    f32x4 a2[8];
    #pragma unroll
    for (int nt = 0; nt < 8; nt++) a2[nt] = zero4();
    #pragma unroll
    for (int ks = 0; ks < 4; ks++){
      short8 a = frag_ld(mybuf + ks * 32, 136);
      #pragma unroll
      for (int nt = 0; nt < 8; nt++)
        a2[nt] = mfma16(a, frag_ld(w1s + nt * 16 * 136 + ks * 32, 136), a2[nt]);
    }
    #pragma unroll
    for (int nt = 0; nt < 8; nt++)
      acc_store_lds(mybuf, 136, nt * 16, a2[nt], b1v[nt], false);
    u16* dst = phi + (size_t)(b * Tc + tt) * 128;
    #pragma unroll
    for (int j = 0; j < 4; j++){
      int c = j * 64 + l;
      int row = c >> 4, k = (c & 15) * 8;
      *(short8*)(dst + row * 128 + k) = *(const short8*)(mybuf + row * 136 + k);
    }
  }
}

// ---------------- phase B: 2-layer GRU, layer-pipelined, 1 barrier/iter ----------------
// Register weights (W[4][3][4] -> AGPRs); h tiles row-major padded LDS [16][136];
// phi: coalesced global->reg (2-iter slack) -> 4-buffer LDS ring (2-barrier write->read gap);
// all MFMA A-operands come from LDS (no vmcnt on the MFMA path).
__global__ __launch_bounds__(512, 1) void k_gru(const u16* __restrict__ phi,
    const float* __restrict__ gwih, const float* __restrict__ gwhh,
    u16* __restrict__ hst, u16* __restrict__ Hs, int Tc){
  __shared__ __align__(16) u16 h0s[2][16 * 136];
  __shared__ __align__(16) u16 h1s[2][16 * 136];
  __shared__ __align__(16) u16 pb[4][16 * 136];
  const int l = threadIdx.x & 63;
  const int wv = threadIdx.x >> 6;
  const int b0 = blockIdx.x * 16;
  const int m0 = (l >> 4) * 4;
  const int colw = wv * 16 + (l & 15);

  // stationary register weights: W[0]=wih0, W[1]=whh0, W[2]=wih1, W[3]=whh1
  const float* srcs[4] = { gwih, gwhh, gwih + 49152, gwhh + 49152 };
  short8 W[4][3][4];
  #pragma unroll
  for (int mm = 0; mm < 4; mm++){
    #pragma unroll
    for (int g = 0; g < 3; g++){
      int n = g * 128 + colw;
      #pragma unroll
      for (int ks = 0; ks < 4; ks++){
        const float* p = srcs[mm] + (size_t)n * 128 + ks * 32 + ((l >> 4) << 3);
        float4 va = *(const float4*)p;
        float4 vb = *(const float4*)(p + 4);
        short8 f;
        f[0] = (short)f2bf(va.x); f[1] = (short)f2bf(va.y);
        f[2] = (short)f2bf(va.z); f[3] = (short)f2bf(va.w);
        f[4] = (short)f2bf(vb.x); f[5] = (short)f2bf(vb.y);
        f[6] = (short)f2bf(vb.z); f[7] = (short)f2bf(vb.w);
        W[mm][g][ks] = f;
      }
    }
  }
  const int row = threadIdx.x >> 5, k0 = (threadIdx.x & 31) * 4;
  // restore state
  *(uint2*)(&h0s[0][row * 136 + k0]) = *(const uint2*)(hst + (size_t)(b0 + row) * 128 + k0);
  *(uint2*)(&h1s[0][row * 136 + k0]) = *(const uint2*)(hst + 131072 + (size_t)(b0 + row) * 128 + k0);
  float hp0[4], hp1[4];
  #pragma unroll
  for (int r = 0; r < 4; r++){
    hp0[r] = bf2f(hst[(size_t)(b0 + m0 + r) * 128 + colw]);
    hp1[r] = bf2f(hst[131072 + (size_t)(b0 + m0 + r) * 128 + colw]);
  }
  // coalesced per-thread phi source / Hs dest pointers
  const u16* pL = phi + (size_t)(b0 + row) * Tc * 128 + k0;
  u16* Hp = Hs + (size_t)(b0 + row) * Tc * 128 + k0;
  // prologue: pb[0]=phi(0), pb[1]=phi(1); regs pfA=phi(2), pfB=phi(3)
  *(uint2*)(&pb[0][row * 136 + k0]) = *(const uint2*)(pL);
  *(uint2*)(&pb[1][row * 136 + k0]) = *(const uint2*)(pL + 128);
  uint2 pfA = *(const uint2*)(pL + 2 * 128);
  uint2 pfB = *(const uint2*)(pL + 3 * 128);
  __syncthreads();

  // ITER(i): layer1 completes GRU step i-1 (H1 = f(H1_prev, H0[i])); layer0 computes
  // H0[i+1] = f(H0[i], phi(i)). Hs slot (i-1) <- h1 state before step i-1.
  // pb ring: read pb[i&3] (phi(i)); write pb[(i+2)&3] = phi(i+2) (from pf, loaded at i-2);
  // reload pf = phi(i+4).
  auto ITER = [&](int i, int P, int q, uint2& pf){
    short8 a0[4];
    #pragma unroll
    for (int ks = 0; ks < 4; ks++) a0[ks] = frag_ld(h0s[P] + ks * 32, 136);
    if (i > 0){
      short8 a1[4];
      #pragma unroll
      for (int ks = 0; ks < 4; ks++) a1[ks] = frag_ld(h1s[P ^ 1] + ks * 32, 136);
      *(uint2*)(Hp + (size_t)(i - 1) * 128) = *(const uint2*)(&h1s[P ^ 1][row * 136 + k0]);
      f32x4 xr = zero4(), xz = zero4(), xn = zero4();
      f32x4 hr = zero4(), hz = zero4(), hh = zero4();
      #pragma unroll
      for (int ks = 0; ks < 4; ks++){
        xr = mfma16(a0[ks], W[2][0][ks], xr);
        xz = mfma16(a0[ks], W[2][1][ks], xz);
        xn = mfma16(a0[ks], W[2][2][ks], xn);
        hr = mfma16(a1[ks], W[3][0][ks], hr);
        hz = mfma16(a1[ks], W[3][1][ks], hz);
        hh = mfma16(a1[ks], W[3][2][ks], hh);
      }
      #pragma unroll
      for (int r = 0; r < 4; r++){
        float rg = fast_sigm(xr[r] + hr[r]);
        float zg = fast_sigm(xz[r] + hz[r]);
        float ng = fast_tanh(xn[r] + rg * hh[r]);
        float hv = zg * (hp1[r] - ng) + ng;
        hp1[r] = hv;
        h1s[P][(m0 + r) * 136 + colw] = f2bf1(hv);
      }
    }
    if (i < Tc){
      short8 ap[4];
      #pragma unroll
      for (int ks = 0; ks < 4; ks++) ap[ks] = frag_ld(pb[q] + ks * 32, 136);
      f32x4 xr = zero4(), xz = zero4(), xn = zero4();
      f32x4 hr = zero4(), hz = zero4(), hh = zero4();
      #pragma unroll
      for (int ks = 0; ks < 4; ks++){
        xr = mfma16(ap[ks], W[0][0][ks], xr);
        xz = mfma16(ap[ks], W[0][1][ks], xz);
        xn = mfma16(ap[ks], W[0][2][ks], xn);
        hr = mfma16(a0[ks], W[1][0][ks], hr);
        hz = mfma16(a0[ks], W[1][1][ks], hz);
        hh = mfma16(a0[ks], W[1][2][ks], hh);
      }
      // late: stage phi(i+2) into ring; issue load of phi(i+4)
      if (i + 2 < Tc) *(uint2*)(&pb[(q + 2) & 3][row * 136 + k0]) = pf;
      if (i + 4 < Tc) pf = *(const uint2*)(pL + (size_t)(i + 4) * 128);
      #pragma unroll
      for (int r = 0; r < 4; r++){
        float rg = fast_sigm(xr[r] + hr[r]);
        float zg = fast_sigm(xz[r] + hz[r]);
        float ng = fast_tanh(xn[r] + rg * hh[r]);
        float hv = zg * (hp0[r] - ng) + ng;
        hp0[r] = hv;
        h0s[P ^ 1][(m0 + r) * 136 + colw] = f2bf1(hv);
      }
    }
    asm volatile("s_waitcnt lgkmcnt(0)" ::: "memory");
    __builtin_amdgcn_s_barrier();
    asm volatile("" ::: "memory");
  };

  for (int i = 0; i < Tc; i += 4){
    ITER(i + 0, 0, 0, pfA);
    ITER(i + 1, 1, 1, pfB);
    ITER(i + 2, 0, 2, pfA);
    ITER(i + 3, 1, 3, pfB);
  }
  ITER(Tc, 0, 0, pfA);   // epilogue: layer1 of step Tc-1 + Hs slot Tc-1 only
  // save state (Tc even: H0 final in h0s[0], H1 final in h1s[0])
  *(uint2*)(hst + (size_t)(b0 + row) * 128 + k0) = *(const uint2*)(&h0s[0][row * 136 + k0]);
  *(uint2*)(hst + 131072 + (size_t)(b0 + row) * 128 + k0) = *(const uint2*)(&h1s[0][row * 136 + k0]);
}

// ---------------- phase C1: dynn + x_mean/x_logvar ----------------
__global__ __launch_bounds__(512, 2) void k_c1(const u16* __restrict__ phi, const u16* __restrict__ Hs,
    const float* __restrict__ dw0, const float* __restrict__ db0,
    const float* __restrict__ dw1, const float* __restrict__ db1,
    const float* __restrict__ xmw, const float* __restrict__ xmb,
    const float* __restrict__ xlw, const float* __restrict__ xlb,
    u16* __restrict__ xmlv, int Tc){
  __shared__ __align__(16) u16 w0s[128 * 264];
  __shared__ __align__(16) u16 w1s[128 * 136];
  __shared__ __align__(16) u16 xws[32 * 136];
  __shared__ __align__(16) u16 buf[8][16 * 136];
  stage_weights(w0s, dw0, 128, 256, 256);
  stage_weights(w1s, dw1, 128, 128, 128);
  stage_weights(xws, xmw, 16, 128, 128);
  stage_weights(xws + 16 * 136, xlw, 16, 128, 128);
  int wv = threadIdx.x >> 6, l = threadIdx.x & 63;
  u16* mybuf = buf[wv];
  float b0v[8], b1v[8];
  #pragma unroll
  for (int nt = 0; nt < 8; nt++){
    b0v[nt] = db0[nt * 16 + (l & 15)];
    b1v[nt] = db1[nt * 16 + (l & 15)];
  }
  float bxm = xmb[l & 15], bxl = xlb[l & 15];
  __syncthreads();
  int tpb = Tc >> 4;
  int ntile = 1024 * tpb;
  int stride = gridDim.x * 8;
  for (int tile = blockIdx.x * 8 + wv; tile < ntile; tile += stride){
    int b = tile / tpb;
    int tt = (tile - b * tpb) << 4;
    size_t rbase = (size_t)(b * Tc + tt);
    const u16* ap = phi + rbase * 128;
    const u16* hp = Hs + rbase * 128;
    f32x4 acc[8];
    #pragma unroll
    for (int nt = 0; nt < 8; nt++) acc[nt] = zero4();
    #pragma unroll
    for (int ks = 0; ks < 8; ks++){
      short8 a = (ks < 4) ? gfrag(ap, 128, ks) : gfrag(hp, 128, ks - 4);
      #pragma unroll
      for (int nt = 0; nt < 8; nt++)
        acc[nt] = mfma16(a, frag_ld(w0s + nt * 16 * 264 + ks * 32, 264), acc[nt]);
    }
    #pragma unroll
    for (int nt = 0; nt < 8; nt++)
      acc_store_lds(mybuf, 136, nt * 16, acc[nt], b0v[nt], true);
    f32x4 a2[8];
    #pragma unroll
    for (int nt = 0; nt < 8; nt++) a2[nt] = zero4();
    #pragma unroll
    for (int ks = 0; ks < 4; ks++){
      short8 a = frag_ld(mybuf + ks * 32, 136);
      #pragma unroll
      for (int nt = 0; nt < 8; nt++)
        a2[nt] = mfma16(a, frag_ld(w1s + nt * 16 * 136 + ks * 32, 136), a2[nt]);
    }
    #pragma unroll
    for (int nt = 0; nt < 8; nt++)
      acc_store_lds(mybuf, 136, nt * 16, a2[nt], b1v[nt], false);
    f32x4 am = zero4(), al = zero4();
    #pragma unroll
    for (int ks = 0; ks < 4; ks++){
      short8 a = frag_ld(mybuf + ks * 32, 136);
      am = mfma16(a, frag_ld(xws + ks * 32, 136), am);
      al = mfma16(a, frag_ld(xws + 16 * 136 + ks * 32, 136), al);
    }
    acc_store_lds(mybuf, 136, 0, am, bxm, false);
    acc_store_lds(mybuf, 136, 16, al, bxl, false);
    u16* dst = xmlv + rbase * 32;
    int c = l;
    int row = c >> 2, k = (c & 3) * 8;
    *(short8*)(dst + row * 32 + k) = *(const short8*)(mybuf + row * 136 + k);
  }
}

// ---------------- phase C2: phi_x + menn + C@x_mean + loss ----------------
__global__ __launch_bounds__(512, 2) void k_c2(const u16* __restrict__ xmlv, const float* __restrict__ y,
    const float* __restrict__ pw0, const float* __restrict__ pb0,
    const float* __restrict__ pw1, const float* __restrict__ pb1,
    const float* __restrict__ mw0, const float* __restrict__ mb0,
    const float* __restrict__ mw1, const float* __restrict__ mb1,
    const float* __restrict__ Cw, float* __restrict__ out, int t0, int Tc){
  __shared__ __align__(16) u16 pw0s[128 * 40];
  __shared__ __align__(16) u16 pw1s[128 * 136];
  __shared__ __align__(16) u16 mw0s[128 * 136];
  __shared__ __align__(16) u16 mw1s[16 * 136];
  __shared__ __align__(16) u16 Cs[16 * 40];
  __shared__ __align__(16) u16 buf[8][16 * 136];
  stage_weights(pw0s, pw0, 128, 32, 32);
  stage_weights(pw1s, pw1, 128, 128, 128);
  stage_weights(mw0s, mw0, 128, 128, 128);
  stage_weights(mw1s, mw1, 16, 128, 128);
  stage_weights(Cs, Cw, 16, 16, 32);
  int wv = threadIdx.x >> 6, l = threadIdx.x & 63;
  u16* mybuf = buf[wv];
  float bp0v[8], bp1v[8], bm0v[8];
  #pragma unroll
  for (int nt = 0; nt < 8; nt++){
    bp0v[nt] = pb0[nt * 16 + (l & 15)];
    bp1v[nt] = pb1[nt * 16 + (l & 15)];
    bm0v[nt] = mb0[nt * 16 + (l & 15)];
  }
  float bm1 = mb1[l & 15];
  __syncthreads();
  float lacc = 0.f;
  int tpb = Tc >> 4;
  int ntile = 1024 * tpb;
  int stride = gridDim.x * 8;
  for (int tile = blockIdx.x * 8 + wv; tile < ntile; tile += stride){
    int b = tile / tpb;
    int tt = (tile - b * tpb) << 4;
    size_t rbase = (size_t)(b * Tc + tt);
    const u16* xp = xmlv + rbase * 32;
    short8 a0 = gfrag(xp, 32, 0);
    f32x4 acc[8];
    #pragma unroll
    for (int nt = 0; nt < 8; nt++)
      acc[nt] = mfma16(a0, frag_ld(pw0s + nt * 16 * 40, 40), zero4());
    #pragma unroll
    for (int nt = 0; nt < 8; nt++)
      acc_store_lds(mybuf, 136, nt * 16, acc[nt], bp0v[nt], true);
    f32x4 a2[8];
    #pragma unroll
    for (int nt = 0; nt < 8; nt++) a2[nt] = zero4();
    #pragma unroll
    for (int ks = 0; ks < 4; ks++){
      short8 a = frag_ld(mybuf + ks * 32, 136);
      #pragma unroll
      for (int nt = 0; nt < 8; nt++)
        a2[nt] = mfma16(a, frag_ld(pw1s + nt * 16 * 136 + ks * 32, 136), a2[nt]);
    }
    #pragma unroll
    for (int nt = 0; nt < 8; nt++)
      acc_store_lds(mybuf, 136, nt * 16, a2[nt], bp1v[nt], false);
    f32x4 a3[8];
    #pragma unroll
    for (int nt = 0; nt < 8; nt++) a3[nt] = zero4();
    #pragma unroll
    for (int ks = 0; ks < 4; ks++){
      short8 a = frag_ld(mybuf + ks * 32, 136);
      #pragma unroll
      for (int nt = 0; nt < 8; nt++)
        a3[nt] = mfma16(a, frag_ld(mw0s + nt * 16 * 136 + ks * 32, 136), a3[nt]);
    }
    #pragma unroll
    for (int nt = 0; nt < 8; nt++)
      acc_store_lds(mybuf, 136, nt * 16, a3[nt], bm0v[nt], true);
    f32x4 ay = zero4();
    #pragma unroll
    for (int ks = 0; ks < 4; ks++){
      short8 a = frag_ld(mybuf + ks * 32, 136);
      ay = mfma16(a, frag_ld(mw1s + ks * 32, 136), ay);
    }
    f32x4 ac = mfma16(a0, frag_ld(Cs, 40), zero4());
    #pragma unroll
    for (int r = 0; r < 4; r++){
      float yh = ay[r] + bm1 + ac[r];
      int m = (l >> 4) * 4 + r, j = l & 15;
      float d = yh - y[(size_t)(b * 16 + j) * 1024 + t0 + tt + m];
      lacc += d * d;
    }
  }
  #pragma unroll
  for (int off = 32; off > 0; off >>= 1)
    lacc += __shfl_down(lacc, off);
  if (l == 0) atomicAdd(out, lacc);
}

extern "C" void kernel_launch(void* const* d_in, const int* in_sizes, int n_in,
                              void* d_out, int out_size, void* d_ws, size_t ws_size,
                              hipStream_t stream){
  const float* u    = (const float*)d_in[0];
  const float* y    = (const float*)d_in[1];
  const float* h0   = (const float*)d_in[2];
  const float* puw0 = (const float*)d_in[3];
  const float* pub0 = (const float*)d_in[4];
  const float* puw1 = (const float*)d_in[5];
  const float* pub1 = (const float*)d_in[6];
  const float* dw0  = (const float*)d_in[7];
  const float* db0  = (const float*)d_in[8];
  const float* dw1  = (const float*)d_in[9];
  const float* db1  = (const float*)d_in[10];
  const float* xmw  = (const float*)d_in[11];
  const float* xmb  = (const float*)d_in[12];
  const float* xlw  = (const float*)d_in[13];
  const float* xlb  = (const float*)d_in[14];
  const float* pxw0 = (const float*)d_in[15];
  const float* pxb0 = (const float*)d_in[16];
  const float* pxw1 = (const float*)d_in[17];
  const float* pxb1 = (const float*)d_in[18];
  const float* mw0  = (const float*)d_in[19];
  const float* mb0  = (const float*)d_in[20];
  const float* mw1  = (const float*)d_in[21];
  const float* mb1  = (const float*)d_in[22];
  const float* gwih = (const float*)d_in[23];
  const float* gwhh = (const float*)d_in[24];
  const float* Cw   = (const float*)d_in[25];

  char* w = (char*)d_ws;
  u16* hst = (u16*)w; w += (size_t)2 * 1024 * 128 * 2;
  size_t head = (size_t)2 * 1024 * 128 * 2 + 4096;
  size_t avail = (ws_size > head) ? (ws_size - head) : 0;
  int Tc = 1024;
  while (Tc > 64 && (size_t)1024 * (size_t)Tc * (128 + 128 + 32) * 2 > avail) Tc >>= 1;
  u16* phi  = (u16*)w; w += (size_t)1024 * Tc * 128 * 2;
  u16* Hs   = (u16*)w; w += (size_t)1024 * Tc * 128 * 2;
  u16* xmlv = (u16*)w; w += (size_t)1024 * Tc * 32 * 2;

  hipMemsetAsync(d_out, 0, sizeof(float), stream);
  k_inith<<<1024, 256, 0, stream>>>(h0, hst);
  for (int t0 = 0; t0 < 1024; t0 += Tc){
    k_phiu<<<512, 512, 0, stream>>>(u, puw0, pub0, puw1, pub1, phi, t0, Tc);
    k_gru<<<64, 512, 0, stream>>>(phi, gwih, gwhh, hst, Hs, Tc);
    k_c1<<<256, 512, 0, stream>>>(phi, Hs, dw0, db0, dw1, db1, xmw, xmb, xlw, xlb, xmlv, Tc);
    k_c2<<<256, 512, 0, stream>>>(xmlv, y, pxw0, pxb0, pxw1, pxb1, mw0, mb0, mw1, mb1, Cw,
                                  (float*)d_out, t0, Tc);
  }
}

// Round 8
// 3406.678 us; speedup vs baseline: 1.4499x; 1.0587x over previous
//
#include <hip/hip_runtime.h>
#include <hip/hip_bf16.h>

typedef unsigned short u16;
typedef unsigned int u32;
using short8 = __attribute__((ext_vector_type(8))) short;
using f32x4  = __attribute__((ext_vector_type(4))) float;

#define DEVINL static __device__ __forceinline__

DEVINL float bf2f(u16 u){
  union { unsigned int i; float f; } x; x.i = ((unsigned int)u) << 16; return x.f;
}
DEVINL u16 f2bf(float f){
  union { float f; unsigned int i; } x; x.f = f;
  unsigned int i = x.i;
  return (u16)((i + 0x7FFFu + ((i >> 16) & 1u)) >> 16);
}
// 1-instruction bf16 convert
DEVINL u16 f2bf1(float f){
  __hip_bfloat16 b = __float2bfloat16(f);
  u16 u; __builtin_memcpy(&u, &b, 2); return u;
}
// fast gates: v_exp_f32 (2^x) + v_rcp_f32
DEVINL float fast_sigm(float x){
  float e = __builtin_amdgcn_exp2f(x * -1.442695041f);
  return __builtin_amdgcn_rcpf(1.f + e);
}
DEVINL float fast_tanh(float x){
  x = fminf(fmaxf(x, -10.f), 10.f);
  float e = __builtin_amdgcn_exp2f(x * -2.885390082f);
  return (1.f - e) * __builtin_amdgcn_rcpf(1.f + e);
}
DEVINL f32x4 zero4(){ f32x4 z = {0.f, 0.f, 0.f, 0.f}; return z; }

DEVINL f32x4 mfma16(short8 a, short8 b, f32x4 c){
  return __builtin_amdgcn_mfma_f32_16x16x32_bf16(a, b, c, 0, 0, 0);
}

// lane l: row = l&15, k0 = (l>>4)*8 ; 16B vector read. stride in u16 elements
DEVINL short8 frag_ld(const u16* base, int stride){
  int l = threadIdx.x & 63;
  return *(const short8*)(base + (l & 15) * stride + ((l >> 4) << 3));
}
DEVINL short8 gfrag(const u16* rowbase, int stride, int ks){
  int l = threadIdx.x & 63;
  return *(const short8*)(rowbase + (size_t)(l & 15) * stride + ks * 32 + ((l >> 4) << 3));
}

DEVINL void acc_store_lds(u16* dst, int stride, int col_base, f32x4 acc, float bias, bool relu){
  int l = threadIdx.x & 63;
  int col = col_base + (l & 15);
  int row0 = (l >> 4) * 4;
  #pragma unroll
  for (int r = 0; r < 4; r++){
    float v = acc[r] + bias;
    if (relu) v = fmaxf(v, 0.f);
    dst[(row0 + r) * stride + col] = f2bf(v);
  }
}

DEVINL void stage_weights(u16* dst, const float* src, int N, int K, int Kp){
  int stride = Kp + 8;
  if (Kp > K){
    int padw = Kp - K;
    for (int i = threadIdx.x; i < N * padw; i += blockDim.x){
      int n = i / padw, k = K + (i - (i / padw) * padw);
      dst[n * stride + k] = 0;
    }
  }
  for (int i = threadIdx.x * 4; i < N * K; i += blockDim.x * 4){
    float4 v = *(const float4*)(src + i);
    int n = i / K, k = i - n * K;
    u16* d = dst + n * stride + k;
    d[0] = f2bf(v.x); d[1] = f2bf(v.y); d[2] = f2bf(v.z); d[3] = f2bf(v.w);
  }
}

__global__ __launch_bounds__(256) void k_inith(const float* __restrict__ h0, u16* __restrict__ hst){
  int i = blockIdx.x * 256 + threadIdx.x;
  if (i < 2 * 1024 * 128) hst[i] = f2bf(h0[i]);
}

// ---------------- phase A: phi_u ----------------
__global__ __launch_bounds__(512, 4) void k_phiu(const float* __restrict__ u,
    const float* __restrict__ w0, const float* __restrict__ b0,
    const float* __restrict__ w1, const float* __restrict__ b1,
    u16* __restrict__ phi, int t0, int Tc){
  __shared__ __align__(16) u16 w0s[128 * 40];
  __shared__ __align__(16) u16 w1s[128 * 136];
  __shared__ __align__(16) u16 buf[8][16 * 136];
  stage_weights(w0s, w0, 128, 16, 32);
  stage_weights(w1s, w1, 128, 128, 128);
  int wv = threadIdx.x >> 6, l = threadIdx.x & 63;
  u16* mybuf = buf[wv];
  float b0v[8], b1v[8];
  #pragma unroll
  for (int nt = 0; nt < 8; nt++){
    b0v[nt] = b0[nt * 16 + (l & 15)];
    b1v[nt] = b1[nt * 16 + (l & 15)];
  }
  __syncthreads();
  int tpb = Tc >> 4;
  int ntile = 1024 * tpb;
  int stride = gridDim.x * 8;
  for (int tile = blockIdx.x * 8 + wv; tile < ntile; tile += stride){
    int b = tile / tpb;
    int tt = (tile - b * tpb) << 4;
    int t = l & 15, kb = l >> 4;
    #pragma unroll
    for (int j = 0; j < 4; j++){
      int k = kb + j * 4;
      mybuf[t * 136 + k] = f2bf(u[(size_t)(b * 16 + k) * 1024 + t0 + tt + t]);
      mybuf[t * 136 + 16 + k] = 0;
    }
    short8 a0 = frag_ld(mybuf, 136);
    f32x4 acc[8];
    #pragma unroll
    for (int nt = 0; nt < 8; nt++)
      acc[nt] = mfma16(a0, frag_ld(w0s + nt * 16 * 40, 40), zero4());
    #pragma unroll
    for (int nt = 0; nt < 8; nt++)
      acc_store_lds(mybuf, 136, nt * 16, acc[nt], b0v[nt], true);
    f32x4 a2[8];
    #pragma unroll
    for (int nt = 0; nt < 8; nt++) a2[nt] = zero4();
    #pragma unroll
    for (int ks = 0; ks < 4; ks++){
      short8 a = frag_ld(mybuf + ks * 32, 136);
      #pragma unroll
      for (int nt = 0; nt < 8; nt++)
        a2[nt] = mfma16(a, frag_ld(w1s + nt * 16 * 136 + ks * 32, 136), a2[nt]);
    }
    #pragma unroll
    for (int nt = 0; nt < 8; nt++)
      acc_store_lds(mybuf, 136, nt * 16, a2[nt], b1v[nt], false);
    u16* dst = phi + (size_t)(b * Tc + tt) * 128;
    #pragma unroll
    for (int j = 0; j < 4; j++){
      int c = j * 64 + l;
      int row = c >> 4, k = (c & 15) * 8;
      *(short8*)(dst + row * 128 + k) = *(const short8*)(mybuf + row * 136 + k);
    }
  }
}

// ---------------- phase B: 2-layer GRU, 8 rows/block x 128 blocks, dup-row gates ----------------
// LDS tiles [16][136]; rows 8..15 duplicate rows 0..7 -> MFMA lanes 32-63 duplicate 0-31.
// Lower lanes apply gates to acc elems {0,1}, upper to {2,3}: 2 elements/lane/layer.
// phi: coalesced global->reg (2-iter slack) -> 4-buffer LDS ring; raw 1-barrier/iter.
__global__ __launch_bounds__(512, 1) void k_gru(const u16* __restrict__ phi,
    const float* __restrict__ gwih, const float* __restrict__ gwhh,
    u16* __restrict__ hst, u16* __restrict__ Hs, int Tc){
  __shared__ __align__(16) u16 h0s[2][16 * 136];
  __shared__ __align__(16) u16 h1s[2][16 * 136];
  __shared__ __align__(16) u16 pb[4][16 * 136];
  const int l = threadIdx.x & 63;
  const int wv = threadIdx.x >> 6;
  const int b0 = blockIdx.x * 8;
  const int m0 = (l >> 4) * 4;
  const int colw = wv * 16 + (l & 15);
  const bool up = (l >= 32);
  const int ro = (m0 & 7) + (up ? 2 : 0);   // first owned real row (0..7), 2 owned rows

  // stationary register weights: W[0]=wih0, W[1]=whh0, W[2]=wih1, W[3]=whh1
  const float* srcs[4] = { gwih, gwhh, gwih + 49152, gwhh + 49152 };
  short8 W[4][3][4];
  #pragma unroll
  for (int mm = 0; mm < 4; mm++){
    #pragma unroll
    for (int g = 0; g < 3; g++){
      int n = g * 128 + colw;
      #pragma unroll
      for (int ks = 0; ks < 4; ks++){
        const float* p = srcs[mm] + (size_t)n * 128 + ks * 32 + ((l >> 4) << 3);
        float4 va = *(const float4*)p;
        float4 vb = *(const float4*)(p + 4);
        short8 f;
        f[0] = (short)f2bf(va.x); f[1] = (short)f2bf(va.y);
        f[2] = (short)f2bf(va.z); f[3] = (short)f2bf(va.w);
        f[4] = (short)f2bf(vb.x); f[5] = (short)f2bf(vb.y);
        f[6] = (short)f2bf(vb.z); f[7] = (short)f2bf(vb.w);
        W[mm][g][ks] = f;
      }
    }
  }
  // coalesced per-thread maps: row = tid>>6 (8 rows), k0 = (tid&63)*2 (u32 grain)
  const int row = threadIdx.x >> 6, k0 = (threadIdx.x & 63) * 2;
  // restore state (rows 0..7) + duplicate into rows 8..15
  {
    u32 v0 = *(const u32*)(hst + (size_t)(b0 + row) * 128 + k0);
    u32 v1 = *(const u32*)(hst + 131072 + (size_t)(b0 + row) * 128 + k0);
    *(u32*)(&h0s[0][row * 136 + k0]) = v0;
    *(u32*)(&h0s[0][(row + 8) * 136 + k0]) = v0;
    *(u32*)(&h1s[0][row * 136 + k0]) = v1;
    *(u32*)(&h1s[0][(row + 8) * 136 + k0]) = v1;
  }
  float hp0[2], hp1[2];
  #pragma unroll
  for (int j = 0; j < 2; j++){
    hp0[j] = bf2f(hst[(size_t)(b0 + ro + j) * 128 + colw]);
    hp1[j] = bf2f(hst[131072 + (size_t)(b0 + ro + j) * 128 + colw]);
  }
  // phi source / Hs dest pointers (coalesced)
  const u16* pL = phi + (size_t)(b0 + row) * Tc * 128 + k0;
  u16* Hp = Hs + (size_t)(b0 + row) * Tc * 128 + k0;
  // prologue: pb[0]=phi(0), pb[1]=phi(1) (dup rows); regs pfA=phi(2), pfB=phi(3)
  {
    u32 v0 = *(const u32*)(pL);
    u32 v1 = *(const u32*)(pL + 128);
    *(u32*)(&pb[0][row * 136 + k0]) = v0;
    *(u32*)(&pb[0][(row + 8) * 136 + k0]) = v0;
    *(u32*)(&pb[1][row * 136 + k0]) = v1;
    *(u32*)(&pb[1][(row + 8) * 136 + k0]) = v1;
  }
  u32 pfA = *(const u32*)(pL + 2 * 128);
  u32 pfB = *(const u32*)(pL + 3 * 128);
  __syncthreads();

  // ITER(i): layer1 finishes GRU step i-1; layer0 computes H0[i+1] from (H0[i], phi(i)).
  // Hs slot (i-1) <- h1 state before step i-1 (rows 0..7).
  auto ITER = [&](int i, int P, int q, u32& pf){
    short8 a0[4];
    #pragma unroll
    for (int ks = 0; ks < 4; ks++) a0[ks] = frag_ld(h0s[P] + ks * 32, 136);
    if (i > 0){
      short8 a1[4];
      #pragma unroll
      for (int ks = 0; ks < 4; ks++) a1[ks] = frag_ld(h1s[P ^ 1] + ks * 32, 136);
      *(u32*)(Hp + (size_t)(i - 1) * 128) = *(const u32*)(&h1s[P ^ 1][row * 136 + k0]);
      f32x4 xr = zero4(), xz = zero4(), xn = zero4();
      f32x4 hr = zero4(), hz = zero4(), hh = zero4();
      #pragma unroll
      for (int ks = 0; ks < 4; ks++){
        xr = mfma16(a0[ks], W[2][0][ks], xr);
        xz = mfma16(a0[ks], W[2][1][ks], xz);
        xn = mfma16(a0[ks], W[2][2][ks], xn);
        hr = mfma16(a1[ks], W[3][0][ks], hr);
        hz = mfma16(a1[ks], W[3][1][ks], hz);
        hh = mfma16(a1[ks], W[3][2][ks], hh);
      }
      #pragma unroll
      for (int j = 0; j < 2; j++){
        float vxr = up ? xr[2 + j] : xr[j];
        float vxz = up ? xz[2 + j] : xz[j];
        float vxn = up ? xn[2 + j] : xn[j];
        float vhr = up ? hr[2 + j] : hr[j];
        float vhz = up ? hz[2 + j] : hz[j];
        float vhh = up ? hh[2 + j] : hh[j];
        float rg = fast_sigm(vxr + vhr);
        float zg = fast_sigm(vxz + vhz);
        float ng = fast_tanh(vxn + rg * vhh);
        float hv = zg * (hp1[j] - ng) + ng;
        hp1[j] = hv;
        u16 hb = f2bf1(hv);
        h1s[P][(ro + j) * 136 + colw] = hb;
        h1s[P][(ro + j + 8) * 136 + colw] = hb;
      }
    }
    if (i < Tc){
      short8 ap[4];
      #pragma unroll
      for (int ks = 0; ks < 4; ks++) ap[ks] = frag_ld(pb[q] + ks * 32, 136);
      f32x4 xr = zero4(), xz = zero4(), xn = zero4();
      f32x4 hr = zero4(), hz = zero4(), hh = zero4();
      #pragma unroll
      for (int ks = 0; ks < 4; ks++){
        xr = mfma16(ap[ks], W[0][0][ks], xr);
        xz = mfma16(ap[ks], W[0][1][ks], xz);
        xn = mfma16(ap[ks], W[0][2][ks], xn);
        hr = mfma16(a0[ks], W[1][0][ks], hr);
        hz = mfma16(a0[ks], W[1][1][ks], hz);
        hh = mfma16(a0[ks], W[1][2][ks], hh);
      }
      // late: stage phi(i+2) into ring (dup rows); issue load of phi(i+4)
      if (i + 2 < Tc){
        *(u32*)(&pb[(q + 2) & 3][row * 136 + k0]) = pf;
        *(u32*)(&pb[(q + 2) & 3][(row + 8) * 136 + k0]) = pf;
      }
      if (i + 4 < Tc) pf = *(const u32*)(pL + (size_t)(i + 4) * 128);
      #pragma unroll
      for (int j = 0; j < 2; j++){
        float vxr = up ? xr[2 + j] : xr[j];
        float vxz = up ? xz[2 + j] : xz[j];
        float vxn = up ? xn[2 + j] : xn[j];
        float vhr = up ? hr[2 + j] : hr[j];
        float vhz = up ? hz[2 + j] : hz[j];
        float vhh = up ? hh[2 + j] : hh[j];
        float rg = fast_sigm(vxr + vhr);
        float zg = fast_sigm(vxz + vhz);
        float ng = fast_tanh(vxn + rg * vhh);
        float hv = zg * (hp0[j] - ng) + ng;
        hp0[j] = hv;
        u16 hb = f2bf1(hv);
        h0s[P ^ 1][(ro + j) * 136 + colw] = hb;
        h0s[P ^ 1][(ro + j + 8) * 136 + colw] = hb;
      }
    }
    asm volatile("s_waitcnt lgkmcnt(0)" ::: "memory");
    __builtin_amdgcn_s_barrier();
    asm volatile("" ::: "memory");
  };

  for (int i = 0; i < Tc; i += 4){
    ITER(i + 0, 0, 0, pfA);
    ITER(i + 1, 1, 1, pfB);
    ITER(i + 2, 0, 2, pfA);
    ITER(i + 3, 1, 3, pfB);
  }
  ITER(Tc, 0, 0, pfA);   // epilogue: layer1 of step Tc-1 + Hs slot Tc-1
  // save state (rows 0..7; Tc even -> finals in h0s[0], h1s[0])
  *(u32*)(hst + (size_t)(b0 + row) * 128 + k0) = *(const u32*)(&h0s[0][row * 136 + k0]);
  *(u32*)(hst + 131072 + (size_t)(b0 + row) * 128 + k0) = *(const u32*)(&h1s[0][row * 136 + k0]);
}

// ---------------- phase C1: dynn + x_mean/x_logvar ----------------
__global__ __launch_bounds__(512, 2) void k_c1(const u16* __restrict__ phi, const u16* __restrict__ Hs,
    const float* __restrict__ dw0, const float* __restrict__ db0,
    const float* __restrict__ dw1, const float* __restrict__ db1,
    const float* __restrict__ xmw, const float* __restrict__ xmb,
    const float* __restrict__ xlw, const float* __restrict__ xlb,
    u16* __restrict__ xmlv, int Tc){
  __shared__ __align__(16) u16 w0s[128 * 264];
  __shared__ __align__(16) u16 w1s[128 * 136];
  __shared__ __align__(16) u16 xws[32 * 136];
  __shared__ __align__(16) u16 buf[8][16 * 136];
  stage_weights(w0s, dw0, 128, 256, 256);
  stage_weights(w1s, dw1, 128, 128, 128);
  stage_weights(xws, xmw, 16, 128, 128);
  stage_weights(xws + 16 * 136, xlw, 16, 128, 128);
  int wv = threadIdx.x >> 6, l = threadIdx.x & 63;
  u16* mybuf = buf[wv];
  float b0v[8], b1v[8];
  #pragma unroll
  for (int nt = 0; nt < 8; nt++){
    b0v[nt] = db0[nt * 16 + (l & 15)];
    b1v[nt] = db1[nt * 16 + (l & 15)];
  }
  float bxm = xmb[l & 15], bxl = xlb[l & 15];
  __syncthreads();
  int tpb = Tc >> 4;
  int ntile = 1024 * tpb;
  int stride = gridDim.x * 8;
  for (int tile = blockIdx.x * 8 + wv; tile < ntile; tile += stride){
    int b = tile / tpb;
    int tt = (tile - b * tpb) << 4;
    size_t rbase = (size_t)(b * Tc + tt);
    const u16* ap = phi + rbase * 128;
    const u16* hp = Hs + rbase * 128;
    f32x4 acc[8];
    #pragma unroll
    for (int nt = 0; nt < 8; nt++) acc[nt] = zero4();
    #pragma unroll
    for (int ks = 0; ks < 8; ks++){
      short8 a = (ks < 4) ? gfrag(ap, 128, ks) : gfrag(hp, 128, ks - 4);
      #pragma unroll
      for (int nt = 0; nt < 8; nt++)
        acc[nt] = mfma16(a, frag_ld(w0s + nt * 16 * 264 + ks * 32, 264), acc[nt]);
    }
    #pragma unroll
    for (int nt = 0; nt < 8; nt++)
      acc_store_lds(mybuf, 136, nt * 16, acc[nt], b0v[nt], true);
    f32x4 a2[8];
    #pragma unroll
    for (int nt = 0; nt < 8; nt++) a2[nt] = zero4();
    #pragma unroll
    for (int ks = 0; ks < 4; ks++){
      short8 a = frag_ld(mybuf + ks * 32, 136);
      #pragma unroll
      for (int nt = 0; nt < 8; nt++)
        a2[nt] = mfma16(a, frag_ld(w1s + nt * 16 * 136 + ks * 32, 136), a2[nt]);
    }
    #pragma unroll
    for (int nt = 0; nt < 8; nt++)
      acc_store_lds(mybuf, 136, nt * 16, a2[nt], b1v[nt], false);
    f32x4 am = zero4(), al = zero4();
    #pragma unroll
    for (int ks = 0; ks < 4; ks++){
      short8 a = frag_ld(mybuf + ks * 32, 136);
      am = mfma16(a, frag_ld(xws + ks * 32, 136), am);
      al = mfma16(a, frag_ld(xws + 16 * 136 + ks * 32, 136), al);
    }
    acc_store_lds(mybuf, 136, 0, am, bxm, false);
    acc_store_lds(mybuf, 136, 16, al, bxl, false);
    u16* dst = xmlv + rbase * 32;
    int c = l;
    int row = c >> 2, k = (c & 3) * 8;
    *(short8*)(dst + row * 32 + k) = *(const short8*)(mybuf + row * 136 + k);
  }
}

// ---------------- phase C2: phi_x + menn + C@x_mean + loss ----------------
__global__ __launch_bounds__(512, 2) void k_c2(const u16* __restrict__ xmlv, const float* __restrict__ y,
    const float* __restrict__ pw0, const float* __restrict__ pb0,
    const float* __restrict__ pw1, const float* __restrict__ pb1,
    const float* __restrict__ mw0, const float* __restrict__ mb0,
    const float* __restrict__ mw1, const float* __restrict__ mb1,
    const float* __restrict__ Cw, float* __restrict__ out, int t0, int Tc){
  __shared__ __align__(16) u16 pw0s[128 * 40];
  __shared__ __align__(16) u16 pw1s[128 * 136];
  __shared__ __align__(16) u16 mw0s[128 * 136];
  __shared__ __align__(16) u16 mw1s[16 * 136];
  __shared__ __align__(16) u16 Cs[16 * 40];
  __shared__ __align__(16) u16 buf[8][16 * 136];
  stage_weights(pw0s, pw0, 128, 32, 32);
  stage_weights(pw1s, pw1, 128, 128, 128);
  stage_weights(mw0s, mw0, 128, 128, 128);
  stage_weights(mw1s, mw1, 16, 128, 128);
  stage_weights(Cs, Cw, 16, 16, 32);
  int wv = threadIdx.x >> 6, l = threadIdx.x & 63;
  u16* mybuf = buf[wv];
  float bp0v[8], bp1v[8], bm0v[8];
  #pragma unroll
  for (int nt = 0; nt < 8; nt++){
    bp0v[nt] = pb0[nt * 16 + (l & 15)];
    bp1v[nt] = pb1[nt * 16 + (l & 15)];
    bm0v[nt] = mb0[nt * 16 + (l & 15)];
  }
  float bm1 = mb1[l & 15];
  __syncthreads();
  float lacc = 0.f;
  int tpb = Tc >> 4;
  int ntile = 1024 * tpb;
  int stride = gridDim.x * 8;
  for (int tile = blockIdx.x * 8 + wv; tile < ntile; tile += stride){
    int b = tile / tpb;
    int tt = (tile - b * tpb) << 4;
    size_t rbase = (size_t)(b * Tc + tt);
    const u16* xp = xmlv + rbase * 32;
    short8 a0 = gfrag(xp, 32, 0);
    f32x4 acc[8];
    #pragma unroll
    for (int nt = 0; nt < 8; nt++)
      acc[nt] = mfma16(a0, frag_ld(pw0s + nt * 16 * 40, 40), zero4());
    #pragma unroll
    for (int nt = 0; nt < 8; nt++)
      acc_store_lds(mybuf, 136, nt * 16, acc[nt], bp0v[nt], true);
    f32x4 a2[8];
    #pragma unroll
    for (int nt = 0; nt < 8; nt++) a2[nt] = zero4();
    #pragma unroll
    for (int ks = 0; ks < 4; ks++){
      short8 a = frag_ld(mybuf + ks * 32, 136);
      #pragma unroll
      for (int nt = 0; nt < 8; nt++)
        a2[nt] = mfma16(a, frag_ld(pw1s + nt * 16 * 136 + ks * 32, 136), a2[nt]);
    }
    #pragma unroll
    for (int nt = 0; nt < 8; nt++)
      acc_store_lds(mybuf, 136, nt * 16, a2[nt], bp1v[nt], false);
    f32x4 a3[8];
    #pragma unroll
    for (int nt = 0; nt < 8; nt++) a3[nt] = zero4();
    #pragma unroll
    for (int ks = 0; ks < 4; ks++){
      short8 a = frag_ld(mybuf + ks * 32, 136);
      #pragma unroll
      for (int nt = 0; nt < 8; nt++)
        a3[nt] = mfma16(a, frag_ld(mw0s + nt * 16 * 136 + ks * 32, 136), a3[nt]);
    }
    #pragma unroll
    for (int nt = 0; nt < 8; nt++)
      acc_store_lds(mybuf, 136, nt * 16, a3[nt], bm0v[nt], true);
    f32x4 ay = zero4();
    #pragma unroll
    for (int ks = 0; ks < 4; ks++){
      short8 a = frag_ld(mybuf + ks * 32, 136);
      ay = mfma16(a, frag_ld(mw1s + ks * 32, 136), ay);
    }
    f32x4 ac = mfma16(a0, frag_ld(Cs, 40), zero4());
    #pragma unroll
    for (int r = 0; r < 4; r++){
      float yh = ay[r] + bm1 + ac[r];
      int m = (l >> 4) * 4 + r, j = l & 15;
      float d = yh - y[(size_t)(b * 16 + j) * 1024 + t0 + tt + m];
      lacc += d * d;
    }
  }
  #pragma unroll
  for (int off = 32; off > 0; off >>= 1)
    lacc += __shfl_down(lacc, off);
  if (l == 0) atomicAdd(out, lacc);
}

extern "C" void kernel_launch(void* const* d_in, const int* in_sizes, int n_in,
                              void* d_out, int out_size, void* d_ws, size_t ws_size,
                              hipStream_t stream){
  const float* u    = (const float*)d_in[0];
  const float* y    = (const float*)d_in[1];
  const float* h0   = (const float*)d_in[2];
  const float* puw0 = (const float*)d_in[3];
  const float* pub0 = (const float*)d_in[4];
  const float* puw1 = (const float*)d_in[5];
  const float* pub1 = (const float*)d_in[6];
  const float* dw0  = (const float*)d_in[7];
  const float* db0  = (const float*)d_in[8];
  const float* dw1  = (const float*)d_in[9];
  const float* db1  = (const float*)d_in[10];
  const float* xmw  = (const float*)d_in[11];
  const float* xmb  = (const float*)d_in[12];
  const float* xlw  = (const float*)d_in[13];
  const float* xlb  = (const float*)d_in[14];
  const float* pxw0 = (const float*)d_in[15];
  const float* pxb0 = (const float*)d_in[16];
  const float* pxw1 = (const float*)d_in[17];
  const float* pxb1 = (const float*)d_in[18];
  const float* mw0  = (const float*)d_in[19];
  const float* mb0  = (const float*)d_in[20];
  const float* mw1  = (const float*)d_in[21];
  const float* mb1  = (const float*)d_in[22];
  const float* gwih = (const float*)d_in[23];
  const float* gwhh = (const float*)d_in[24];
  const float* Cw   = (const float*)d_in[25];

  char* w = (char*)d_ws;
  u16* hst = (u16*)w; w += (size_t)2 * 1024 * 128 * 2;
  size_t head = (size_t)2 * 1024 * 128 * 2 + 4096;
  size_t avail = (ws_size > head) ? (ws_size - head) : 0;
  int Tc = 1024;
  while (Tc > 64 && (size_t)1024 * (size_t)Tc * (128 + 128 + 32) * 2 > avail) Tc >>= 1;
  u16* phi  = (u16*)w; w += (size_t)1024 * Tc * 128 * 2;
  u16* Hs   = (u16*)w; w += (size_t)1024 * Tc * 128 * 2;
  u16* xmlv = (u16*)w; w += (size_t)1024 * Tc * 32 * 2;

  hipMemsetAsync(d_out, 0, sizeof(float), stream);
  k_inith<<<1024, 256, 0, stream>>>(h0, hst);
  for (int t0 = 0; t0 < 1024; t0 += Tc){
    k_phiu<<<512, 512, 0, stream>>>(u, puw0, pub0, puw1, pub1, phi, t0, Tc);
    k_gru<<<128, 512, 0, stream>>>(phi, gwih, gwhh, hst, Hs, Tc);
    k_c1<<<256, 512, 0, stream>>>(phi, Hs, dw0, db0, dw1, db1, xmw, xmb, xlw, xlb, xmlv, Tc);
    k_c2<<<256, 512, 0, stream>>>(xmlv, y, pxw0, pxb0, pxw1, pxb1, mw0, mb0, mw1, mb1, Cw,
                                  (float*)d_out, t0, Tc);
  }
}

// Round 9
// 3378.083 us; speedup vs baseline: 1.4622x; 1.0085x over previous
//
#include <hip/hip_runtime.h>
#include <hip/hip_bf16.h>

typedef unsigned short u16;
typedef unsigned int u32;
using short8 = __attribute__((ext_vector_type(8))) short;
using f32x4  = __attribute__((ext_vector_type(4))) float;

#define DEVINL static __device__ __forceinline__

DEVINL float bf2f(u16 u){
  union { unsigned int i; float f; } x; x.i = ((unsigned int)u) << 16; return x.f;
}
DEVINL u16 f2bf(float f){
  union { float f; unsigned int i; } x; x.f = f;
  unsigned int i = x.i;
  return (u16)((i + 0x7FFFu + ((i >> 16) & 1u)) >> 16);
}
DEVINL u16 f2bf1(float f){
  __hip_bfloat16 b = __float2bfloat16(f);
  u16 u; __builtin_memcpy(&u, &b, 2); return u;
}
DEVINL float fast_sigm(float x){
  float e = __builtin_amdgcn_exp2f(x * -1.442695041f);
  return __builtin_amdgcn_rcpf(1.f + e);
}
DEVINL float fast_tanh(float x){
  x = fminf(fmaxf(x, -10.f), 10.f);
  float e = __builtin_amdgcn_exp2f(x * -2.885390082f);
  return (1.f - e) * __builtin_amdgcn_rcpf(1.f + e);
}
DEVINL f32x4 zero4(){ f32x4 z = {0.f, 0.f, 0.f, 0.f}; return z; }

DEVINL f32x4 mfma16(short8 a, short8 b, f32x4 c){
  return __builtin_amdgcn_mfma_f32_16x16x32_bf16(a, b, c, 0, 0, 0);
}

// lane l: row = l&15, k0 = (l>>4)*8 ; 16B vector read. stride in u16 elements
DEVINL short8 frag_ld(const u16* base, int stride){
  int l = threadIdx.x & 63;
  return *(const short8*)(base + (l & 15) * stride + ((l >> 4) << 3));
}
DEVINL short8 gfrag(const u16* rowbase, int stride, int ks){
  int l = threadIdx.x & 63;
  return *(const short8*)(rowbase + (size_t)(l & 15) * stride + ks * 32 + ((l >> 4) << 3));
}

DEVINL void acc_store_lds(u16* dst, int stride, int col_base, f32x4 acc, float bias, bool relu){
  int l = threadIdx.x & 63;
  int col = col_base + (l & 15);
  int row0 = (l >> 4) * 4;
  #pragma unroll
  for (int r = 0; r < 4; r++){
    float v = acc[r] + bias;
    if (relu) v = fmaxf(v, 0.f);
    dst[(row0 + r) * stride + col] = f2bf(v);
  }
}

DEVINL void stage_weights(u16* dst, const float* src, int N, int K, int Kp){
  int stride = Kp + 8;
  if (Kp > K){
    int padw = Kp - K;
    for (int i = threadIdx.x; i < N * padw; i += blockDim.x){
      int n = i / padw, k = K + (i - (i / padw) * padw);
      dst[n * stride + k] = 0;
    }
  }
  for (int i = threadIdx.x * 4; i < N * K; i += blockDim.x * 4){
    float4 v = *(const float4*)(src + i);
    int n = i / K, k = i - n * K;
    u16* d = dst + n * stride + k;
    d[0] = f2bf(v.x); d[1] = f2bf(v.y); d[2] = f2bf(v.z); d[3] = f2bf(v.w);
  }
}

__global__ __launch_bounds__(256) void k_inith(const float* __restrict__ h0, u16* __restrict__ hst){
  int i = blockIdx.x * 256 + threadIdx.x;
  if (i < 2 * 1024 * 128) hst[i] = f2bf(h0[i]);
}

// ---------------- phase A: phi_u ----------------
__global__ __launch_bounds__(512, 4) void k_phiu(const float* __restrict__ u,
    const float* __restrict__ w0, const float* __restrict__ b0,
    const float* __restrict__ w1, const float* __restrict__ b1,
    u16* __restrict__ phi, int t0, int Tc){
  __shared__ __align__(16) u16 w0s[128 * 40];
  __shared__ __align__(16) u16 w1s[128 * 136];
  __shared__ __align__(16) u16 buf[8][16 * 136];
  stage_weights(w0s, w0, 128, 16, 32);
  stage_weights(w1s, w1, 128, 128, 128);
  int wv = threadIdx.x >> 6, l = threadIdx.x & 63;
  u16* mybuf = buf[wv];
  float b0v[8], b1v[8];
  #pragma unroll
  for (int nt = 0; nt < 8; nt++){
    b0v[nt] = b0[nt * 16 + (l & 15)];
    b1v[nt] = b1[nt * 16 + (l & 15)];
  }
  __syncthreads();
  int tpb = Tc >> 4;
  int ntile = 1024 * tpb;
  int stride = gridDim.x * 8;
  for (int tile = blockIdx.x * 8 + wv; tile < ntile; tile += stride){
    int b = tile / tpb;
    int tt = (tile - b * tpb) << 4;
    int t = l & 15, kb = l >> 4;
    #pragma unroll
    for (int j = 0; j < 4; j++){
      int k = kb + j * 4;
      mybuf[t * 136 + k] = f2bf(u[(size_t)(b * 16 + k) * 1024 + t0 + tt + t]);
      mybuf[t * 136 + 16 + k] = 0;
    }
    short8 a0 = frag_ld(mybuf, 136);
    f32x4 acc[8];
    #pragma unroll
    for (int nt = 0; nt < 8; nt++)
      acc[nt] = mfma16(a0, frag_ld(w0s + nt * 16 * 40, 40), zero4());
    #pragma unroll
    for (int nt = 0; nt < 8; nt++)
      acc_store_lds(mybuf, 136, nt * 16, acc[nt], b0v[nt], true);
    f32x4 a2[8];
    #pragma unroll
    for (int nt = 0; nt < 8; nt++) a2[nt] = zero4();
    #pragma unroll
    for (int ks = 0; ks < 4; ks++){
      short8 a = frag_ld(mybuf + ks * 32, 136);
      #pragma unroll
      for (int nt = 0; nt < 8; nt++)
        a2[nt] = mfma16(a, frag_ld(w1s + nt * 16 * 136 + ks * 32, 136), a2[nt]);
    }
    #pragma unroll
    for (int nt = 0; nt < 8; nt++)
      acc_store_lds(mybuf, 136, nt * 16, a2[nt], b1v[nt], false);
    u16* dst = phi + (size_t)(b * Tc + tt) * 128;
    #pragma unroll
    for (int j = 0; j < 4; j++){
      int c = j * 64 + l;
      int row = c >> 4, k = (c & 15) * 8;
      *(short8*)(dst + row * 128 + k) = *(const short8*)(mybuf + row * 136 + k);
    }
  }
}

// ---------------- phase B: 2-layer GRU, 4 waves x 16 rows x 32 neurons/wave ----------------
// 64 blocks. wih0 in LDS; whh0/wih1/whh1 register-resident at 2 n-tiles/wave (288 regs).
// r/z gates: input+hidden fused into one accumulator chain. 1 raw barrier/iter.
// phi: coalesced global->reg -> 4-buffer LDS ring. Halves per-CU redundant A-frag LDS reads.
__global__ __launch_bounds__(256, 1) void k_gru(const u16* __restrict__ phi,
    const float* __restrict__ gwih, const float* __restrict__ gwhh,
    u16* __restrict__ hst, u16* __restrict__ Hs, int Tc){
  __shared__ __align__(16) u16 wi0[384 * 136];     // 104448 B
  __shared__ __align__(16) u16 h0s[2][16 * 136];
  __shared__ __align__(16) u16 h1s[2][16 * 136];
  __shared__ __align__(16) u16 pb[4][16 * 136];
  const int l = threadIdx.x & 63;
  const int wv = threadIdx.x >> 6;          // 0..3
  const int b0 = blockIdx.x * 16;
  const int m0 = (l >> 4) * 4;
  const int cc = l & 15;
  const int nb = wv * 32;                   // neuron base of this wave (2 tiles: nb, nb+16)

  stage_weights(wi0, gwih, 384, 128, 128);  // layer0 W_ih in LDS

  // register weights: Wr[0]=whh0, Wr[1]=wih1, Wr[2]=whh1 ; [mat][gate][ntile][ks]
  const float* srcs[3] = { gwhh, gwih + 49152, gwhh + 49152 };
  short8 Wr[3][3][2][4];
  #pragma unroll
  for (int mm = 0; mm < 3; mm++){
    #pragma unroll
    for (int g = 0; g < 3; g++){
      #pragma unroll
      for (int nt = 0; nt < 2; nt++){
        int n = g * 128 + nb + nt * 16 + cc;
        #pragma unroll
        for (int ks = 0; ks < 4; ks++){
          const float* p = srcs[mm] + (size_t)n * 128 + ks * 32 + ((l >> 4) << 3);
          float4 va = *(const float4*)p;
          float4 vb = *(const float4*)(p + 4);
          short8 f;
          f[0] = (short)f2bf(va.x); f[1] = (short)f2bf(va.y);
          f[2] = (short)f2bf(va.z); f[3] = (short)f2bf(va.w);
          f[4] = (short)f2bf(vb.x); f[5] = (short)f2bf(vb.y);
          f[6] = (short)f2bf(vb.z); f[7] = (short)f2bf(vb.w);
          Wr[mm][g][nt][ks] = f;
        }
      }
    }
  }
  // per-thread copy map: 256 threads x 16B covers one 16x128 tile
  const int row = threadIdx.x >> 4, k0 = (threadIdx.x & 15) * 8;
  // restore state
  *(uint4*)(&h0s[0][row * 136 + k0]) = *(const uint4*)(hst + (size_t)(b0 + row) * 128 + k0);
  *(uint4*)(&h1s[0][row * 136 + k0]) = *(const uint4*)(hst + 131072 + (size_t)(b0 + row) * 128 + k0);
  float hp0[2][4], hp1[2][4];
  #pragma unroll
  for (int nt = 0; nt < 2; nt++)
    #pragma unroll
    for (int r = 0; r < 4; r++){
      hp0[nt][r] = bf2f(hst[(size_t)(b0 + m0 + r) * 128 + nb + nt * 16 + cc]);
      hp1[nt][r] = bf2f(hst[131072 + (size_t)(b0 + m0 + r) * 128 + nb + nt * 16 + cc]);
    }
  // phi source / Hs dest pointers (coalesced, 16B grain)
  const u16* pL = phi + (size_t)(b0 + row) * Tc * 128 + k0;
  u16* Hp = Hs + (size_t)(b0 + row) * Tc * 128 + k0;
  // prologue: pb[0]=phi(0), pb[1]=phi(1); regs pfA=phi(2), pfB=phi(3)
  *(uint4*)(&pb[0][row * 136 + k0]) = *(const uint4*)(pL);
  *(uint4*)(&pb[1][row * 136 + k0]) = *(const uint4*)(pL + 128);
  uint4 pfA = *(const uint4*)(pL + 2 * 128);
  uint4 pfB = *(const uint4*)(pL + 3 * 128);
  __syncthreads();

  // ITER(i): layer1 finishes GRU step i-1 (reads h0s[P]=H0[i], h1s[P^1]=H1[i-1] -> h1s[P]);
  //          layer0 computes H0[i+1] from (h0s[P], phi(i) in pb[q]) -> h0s[P^1].
  auto ITER = [&](int i, int P, int q, uint4& pf){
    short8 a0[4];
    #pragma unroll
    for (int ks = 0; ks < 4; ks++) a0[ks] = frag_ld(h0s[P] + ks * 32, 136);
    if (i > 0){
      short8 a1[4];
      #pragma unroll
      for (int ks = 0; ks < 4; ks++) a1[ks] = frag_ld(h1s[P ^ 1] + ks * 32, 136);
      *(uint4*)(Hp + (size_t)(i - 1) * 128) = *(const uint4*)(&h1s[P ^ 1][row * 136 + k0]);
      f32x4 cr[2], cz[2], cin[2], chn[2];
      #pragma unroll
      for (int nt = 0; nt < 2; nt++){ cr[nt]=zero4(); cz[nt]=zero4(); cin[nt]=zero4(); chn[nt]=zero4(); }
      #pragma unroll
      for (int ks = 0; ks < 4; ks++)
        #pragma unroll
        for (int nt = 0; nt < 2; nt++){
          cr[nt]  = mfma16(a0[ks], Wr[1][0][nt][ks], cr[nt]);   // wih1
          cr[nt]  = mfma16(a1[ks], Wr[2][0][nt][ks], cr[nt]);   // whh1
          cz[nt]  = mfma16(a0[ks], Wr[1][1][nt][ks], cz[nt]);
          cz[nt]  = mfma16(a1[ks], Wr[2][1][nt][ks], cz[nt]);
          cin[nt] = mfma16(a0[ks], Wr[1][2][nt][ks], cin[nt]);
          chn[nt] = mfma16(a1[ks], Wr[2][2][nt][ks], chn[nt]);
        }
      #pragma unroll
      for (int nt = 0; nt < 2; nt++)
        #pragma unroll
        for (int r = 0; r < 4; r++){
          float rg = fast_sigm(cr[nt][r]);
          float zg = fast_sigm(cz[nt][r]);
          float ng = fast_tanh(cin[nt][r] + rg * chn[nt][r]);
          float hv = zg * (hp1[nt][r] - ng) + ng;
          hp1[nt][r] = hv;
          h1s[P][(m0 + r) * 136 + nb + nt * 16 + cc] = f2bf1(hv);
        }
    }
    if (i < Tc){
      short8 ap[4];
      #pragma unroll
      for (int ks = 0; ks < 4; ks++) ap[ks] = frag_ld(pb[q] + ks * 32, 136);
      f32x4 cr[2], cz[2], cin[2], chn[2];
      #pragma unroll
      for (int nt = 0; nt < 2; nt++){ cr[nt]=zero4(); cz[nt]=zero4(); cin[nt]=zero4(); chn[nt]=zero4(); }
      #pragma unroll
      for (int ks = 0; ks < 4; ks++)
        #pragma unroll
        for (int nt = 0; nt < 2; nt++){
          cr[nt]  = mfma16(ap[ks], frag_ld(wi0 + (0 * 128 + nb + nt * 16) * 136 + ks * 32, 136), cr[nt]);
          cr[nt]  = mfma16(a0[ks], Wr[0][0][nt][ks], cr[nt]);   // whh0
          cz[nt]  = mfma16(ap[ks], frag_ld(wi0 + (1 * 128 + nb + nt * 16) * 136 + ks * 32, 136), cz[nt]);
          cz[nt]  = mfma16(a0[ks], Wr[0][1][nt][ks], cz[nt]);
          cin[nt] = mfma16(ap[ks], frag_ld(wi0 + (2 * 128 + nb + nt * 16) * 136 + ks * 32, 136), cin[nt]);
          chn[nt] = mfma16(a0[ks], Wr[0][2][nt][ks], chn[nt]);
        }
      // late: stage phi(i+2) into ring; issue load of phi(i+4)
      if (i + 2 < Tc) *(uint4*)(&pb[(q + 2) & 3][row * 136 + k0]) = pf;
      if (i + 4 < Tc) pf = *(const uint4*)(pL + (size_t)(i + 4) * 128);
      #pragma unroll
      for (int nt = 0; nt < 2; nt++)
        #pragma unroll
        for (int r = 0; r < 4; r++){
          float rg = fast_sigm(cr[nt][r]);
          float zg = fast_sigm(cz[nt][r]);
          float ng = fast_tanh(cin[nt][r] + rg * chn[nt][r]);
          float hv = zg * (hp0[nt][r] - ng) + ng;
          hp0[nt][r] = hv;
          h0s[P ^ 1][(m0 + r) * 136 + nb + nt * 16 + cc] = f2bf1(hv);
        }
    }
    asm volatile("s_waitcnt lgkmcnt(0)" ::: "memory");
    __builtin_amdgcn_s_barrier();
    asm volatile("" ::: "memory");
  };

  for (int i = 0; i < Tc; i += 4){
    ITER(i + 0, 0, 0, pfA);
    ITER(i + 1, 1, 1, pfB);
    ITER(i + 2, 0, 2, pfA);
    ITER(i + 3, 1, 3, pfB);
  }
  ITER(Tc, 0, 0, pfA);   // epilogue: layer1 of step Tc-1 + Hs slot Tc-1
  // save state (Tc even: finals in h0s[0], h1s[0])
  *(uint4*)(hst + (size_t)(b0 + row) * 128 + k0) = *(const uint4*)(&h0s[0][row * 136 + k0]);
  *(uint4*)(hst + 131072 + (size_t)(b0 + row) * 128 + k0) = *(const uint4*)(&h1s[0][row * 136 + k0]);
}

// ---------------- phase C1: dynn + x_mean/x_logvar ----------------
__global__ __launch_bounds__(512, 2) void k_c1(const u16* __restrict__ phi, const u16* __restrict__ Hs,
    const float* __restrict__ dw0, const float* __restrict__ db0,
    const float* __restrict__ dw1, const float* __restrict__ db1,
    const float* __restrict__ xmw, const float* __restrict__ xmb,
    const float* __restrict__ xlw, const float* __restrict__ xlb,
    u16* __restrict__ xmlv, int Tc){
  __shared__ __align__(16) u16 w0s[128 * 264];
  __shared__ __align__(16) u16 w1s[128 * 136];
  __shared__ __align__(16) u16 xws[32 * 136];
  __shared__ __align__(16) u16 buf[8][16 * 136];
  stage_weights(w0s, dw0, 128, 256, 256);
  stage_weights(w1s, dw1, 128, 128, 128);
  stage_weights(xws, xmw, 16, 128, 128);
  stage_weights(xws + 16 * 136, xlw, 16, 128, 128);
  int wv = threadIdx.x >> 6, l = threadIdx.x & 63;
  u16* mybuf = buf[wv];
  float b0v[8], b1v[8];
  #pragma unroll
  for (int nt = 0; nt < 8; nt++){
    b0v[nt] = db0[nt * 16 + (l & 15)];
    b1v[nt] = db1[nt * 16 + (l & 15)];
  }
  float bxm = xmb[l & 15], bxl = xlb[l & 15];
  __syncthreads();
  int tpb = Tc >> 4;
  int ntile = 1024 * tpb;
  int stride = gridDim.x * 8;
  for (int tile = blockIdx.x * 8 + wv; tile < ntile; tile += stride){
    int b = tile / tpb;
    int tt = (tile - b * tpb) << 4;
    size_t rbase = (size_t)(b * Tc + tt);
    const u16* ap = phi + rbase * 128;
    const u16* hp = Hs + rbase * 128;
    f32x4 acc[8];
    #pragma unroll
    for (int nt = 0; nt < 8; nt++) acc[nt] = zero4();
    #pragma unroll
    for (int ks = 0; ks < 8; ks++){
      short8 a = (ks < 4) ? gfrag(ap, 128, ks) : gfrag(hp, 128, ks - 4);
      #pragma unroll
      for (int nt = 0; nt < 8; nt++)
        acc[nt] = mfma16(a, frag_ld(w0s + nt * 16 * 264 + ks * 32, 264), acc[nt]);
    }
    #pragma unroll
    for (int nt = 0; nt < 8; nt++)
      acc_store_lds(mybuf, 136, nt * 16, acc[nt], b0v[nt], true);
    f32x4 a2[8];
    #pragma unroll
    for (int nt = 0; nt < 8; nt++) a2[nt] = zero4();
    #pragma unroll
    for (int ks = 0; ks < 4; ks++){
      short8 a = frag_ld(mybuf + ks * 32, 136);
      #pragma unroll
      for (int nt = 0; nt < 8; nt++)
        a2[nt] = mfma16(a, frag_ld(w1s + nt * 16 * 136 + ks * 32, 136), a2[nt]);
    }
    #pragma unroll
    for (int nt = 0; nt < 8; nt++)
      acc_store_lds(mybuf, 136, nt * 16, a2[nt], b1v[nt], false);
    f32x4 am = zero4(), al = zero4();
    #pragma unroll
    for (int ks = 0; ks < 4; ks++){
      short8 a = frag_ld(mybuf + ks * 32, 136);
      am = mfma16(a, frag_ld(xws + ks * 32, 136), am);
      al = mfma16(a, frag_ld(xws + 16 * 136 + ks * 32, 136), al);
    }
    acc_store_lds(mybuf, 136, 0, am, bxm, false);
    acc_store_lds(mybuf, 136, 16, al, bxl, false);
    u16* dst = xmlv + rbase * 32;
    int c = l;
    int row = c >> 2, k = (c & 3) * 8;
    *(short8*)(dst + row * 32 + k) = *(const short8*)(mybuf + row * 136 + k);
  }
}

// ---------------- phase C2: phi_x + menn + C@x_mean + loss ----------------
__global__ __launch_bounds__(512, 2) void k_c2(const u16* __restrict__ xmlv, const float* __restrict__ y,
    const float* __restrict__ pw0, const float* __restrict__ pb0,
    const float* __restrict__ pw1, const float* __restrict__ pb1,
    const float* __restrict__ mw0, const float* __restrict__ mb0,
    const float* __restrict__ mw1, const float* __restrict__ mb1,
    const float* __restrict__ Cw, float* __restrict__ out, int t0, int Tc){
  __shared__ __align__(16) u16 pw0s[128 * 40];
  __shared__ __align__(16) u16 pw1s[128 * 136];
  __shared__ __align__(16) u16 mw0s[128 * 136];
  __shared__ __align__(16) u16 mw1s[16 * 136];
  __shared__ __align__(16) u16 Cs[16 * 40];
  __shared__ __align__(16) u16 buf[8][16 * 136];
  stage_weights(pw0s, pw0, 128, 32, 32);
  stage_weights(pw1s, pw1, 128, 128, 128);
  stage_weights(mw0s, mw0, 128, 128, 128);
  stage_weights(mw1s, mw1, 16, 128, 128);
  stage_weights(Cs, Cw, 16, 16, 32);
  int wv = threadIdx.x >> 6, l = threadIdx.x & 63;
  u16* mybuf = buf[wv];
  float bp0v[8], bp1v[8], bm0v[8];
  #pragma unroll
  for (int nt = 0; nt < 8; nt++){
    bp0v[nt] = pb0[nt * 16 + (l & 15)];
    bp1v[nt] = pb1[nt * 16 + (l & 15)];
    bm0v[nt] = mb0[nt * 16 + (l & 15)];
  }
  float bm1 = mb1[l & 15];
  __syncthreads();
  float lacc = 0.f;
  int tpb = Tc >> 4;
  int ntile = 1024 * tpb;
  int stride = gridDim.x * 8;
  for (int tile = blockIdx.x * 8 + wv; tile < ntile; tile += stride){
    int b = tile / tpb;
    int tt = (tile - b * tpb) << 4;
    size_t rbase = (size_t)(b * Tc + tt);
    const u16* xp = xmlv + rbase * 32;
    short8 a0 = gfrag(xp, 32, 0);
    f32x4 acc[8];
    #pragma unroll
    for (int nt = 0; nt < 8; nt++)
      acc[nt] = mfma16(a0, frag_ld(pw0s + nt * 16 * 40, 40), zero4());
    #pragma unroll
    for (int nt = 0; nt < 8; nt++)
      acc_store_lds(mybuf, 136, nt * 16, acc[nt], bp0v[nt], true);
    f32x4 a2[8];
    #pragma unroll
    for (int nt = 0; nt < 8; nt++) a2[nt] = zero4();
    #pragma unroll
    for (int ks = 0; ks < 4; ks++){
      short8 a = frag_ld(mybuf + ks * 32, 136);
      #pragma unroll
      for (int nt = 0; nt < 8; nt++)
        a2[nt] = mfma16(a, frag_ld(pw1s + nt * 16 * 136 + ks * 32, 136), a2[nt]);
    }
    #pragma unroll
    for (int nt = 0; nt < 8; nt++)
      acc_store_lds(mybuf, 136, nt * 16, a2[nt], bp1v[nt], false);
    f32x4 a3[8];
    #pragma unroll
    for (int nt = 0; nt < 8; nt++) a3[nt] = zero4();
    #pragma unroll
    for (int ks = 0; ks < 4; ks++){
      short8 a = frag_ld(mybuf + ks * 32, 136);
      #pragma unroll
      for (int nt = 0; nt < 8; nt++)
        a3[nt] = mfma16(a, frag_ld(mw0s + nt * 16 * 136 + ks * 32, 136), a3[nt]);
    }
    #pragma unroll
    for (int nt = 0; nt < 8; nt++)
      acc_store_lds(mybuf, 136, nt * 16, a3[nt], bm0v[nt], true);
    f32x4 ay = zero4();
    #pragma unroll
    for (int ks = 0; ks < 4; ks++){
      short8 a = frag_ld(mybuf + ks * 32, 136);
      ay = mfma16(a, frag_ld(mw1s + ks * 32, 136), ay);
    }
    f32x4 ac = mfma16(a0, frag_ld(Cs, 40), zero4());
    #pragma unroll
    for (int r = 0; r < 4; r++){
      float yh = ay[r] + bm1 + ac[r];
      int m = (l >> 4) * 4 + r, j = l & 15;
      float d = yh - y[(size_t)(b * 16 + j) * 1024 + t0 + tt + m];
      lacc += d * d;
    }
  }
  #pragma unroll
  for (int off = 32; off > 0; off >>= 1)
    lacc += __shfl_down(lacc, off);
  if (l == 0) atomicAdd(out, lacc);
}

extern "C" void kernel_launch(void* const* d_in, const int* in_sizes, int n_in,
                              void* d_out, int out_size, void* d_ws, size_t ws_size,
                              hipStream_t stream){
  const float* u    = (const float*)d_in[0];
  const float* y    = (const float*)d_in[1];
  const float* h0   = (const float*)d_in[2];
  const float* puw0 = (const float*)d_in[3];
  const float* pub0 = (const float*)d_in[4];
  const float* puw1 = (const float*)d_in[5];
  const float* pub1 = (const float*)d_in[6];
  const float* dw0  = (const float*)d_in[7];
  const float* db0  = (const float*)d_in[8];
  const float* dw1  = (const float*)d_in[9];
  const float* db1  = (const float*)d_in[10];
  const float* xmw  = (const float*)d_in[11];
  const float* xmb  = (const float*)d_in[12];
  const float* xlw  = (const float*)d_in[13];
  const float* xlb  = (const float*)d_in[14];
  const float* pxw0 = (const float*)d_in[15];
  const float* pxb0 = (const float*)d_in[16];
  const float* pxw1 = (const float*)d_in[17];
  const float* pxb1 = (const float*)d_in[18];
  const float* mw0  = (const float*)d_in[19];
  const float* mb0  = (const float*)d_in[20];
  const float* mw1  = (const float*)d_in[21];
  const float* mb1  = (const float*)d_in[22];
  const float* gwih = (const float*)d_in[23];
  const float* gwhh = (const float*)d_in[24];
  const float* Cw   = (const float*)d_in[25];

  char* w = (char*)d_ws;
  u16* hst = (u16*)w; w += (size_t)2 * 1024 * 128 * 2;
  size_t head = (size_t)2 * 1024 * 128 * 2 + 4096;
  size_t avail = (ws_size > head) ? (ws_size - head) : 0;
  int Tc = 1024;
  while (Tc > 64 && (size_t)1024 * (size_t)Tc * (128 + 128 + 32) * 2 > avail) Tc >>= 1;
  u16* phi  = (u16*)w; w += (size_t)1024 * Tc * 128 * 2;
  u16* Hs   = (u16*)w; w += (size_t)1024 * Tc * 128 * 2;
  u16* xmlv = (u16*)w; w += (size_t)1024 * Tc * 32 * 2;

  hipMemsetAsync(d_out, 0, sizeof(float), stream);
  k_inith<<<1024, 256, 0, stream>>>(h0, hst);
  for (int t0 = 0; t0 < 1024; t0 += Tc){
    k_phiu<<<512, 512, 0, stream>>>(u, puw0, pub0, puw1, pub1, phi, t0, Tc);
    k_gru<<<64, 256, 0, stream>>>(phi, gwih, gwhh, hst, Hs, Tc);
    k_c1<<<256, 512, 0, stream>>>(phi, Hs, dw0, db0, dw1, db1, xmw, xmb, xlw, xlb, xmlv, Tc);
    k_c2<<<256, 512, 0, stream>>>(xmlv, y, pxw0, pxb0, pxw1, pxb1, mw0, mb0, mw1, mb1, Cw,
                                  (float*)d_out, t0, Tc);
  }
}